// Round 1
// baseline (707.673 us; speedup 1.0000x reference)
//
#include <hip/hip_runtime.h>

typedef __attribute__((ext_vector_type(8))) short short8;
typedef __attribute__((ext_vector_type(4))) float floatx4;

#define T_SIZE 32768
#define OBS    256
#define H      512
#define NC     512     // scan chunks
#define CHUNK  64      // T_SIZE / NC

__device__ __forceinline__ unsigned short f2bf(float f){
    union { float f; unsigned u; } v; v.f = f;
    unsigned u = v.u;
    u += 0x7FFFu + ((u >> 16) & 1u);   // round-to-nearest-even
    return (unsigned short)(u >> 16);
}

// ---- cast x [T,OBS] fp32 -> bf16, vectorized ----
__global__ void cast_x_kernel(const float* __restrict__ x, unsigned short* __restrict__ xb, int n4){
    int i = blockIdx.x * 256 + threadIdx.x;
    if (i < n4){
        float4 v = ((const float4*)x)[i];
        ushort4 o;
        o.x = f2bf(v.x); o.y = f2bf(v.y); o.z = f2bf(v.z); o.w = f2bf(v.w);
        ((ushort4*)xb)[i] = o;
    }
}

// ---- transpose+cast weight W[K][512] fp32 -> dst[n][k] bf16 ----
__global__ void tcast_kernel(const float* __restrict__ W, unsigned short* __restrict__ dst, int K){
    int idx = blockIdx.x * 256 + threadIdx.x;
    if (idx < K * H){
        int k = idx >> 9;        // H == 512
        int n = idx & 511;
        dst[(size_t)n * K + k] = f2bf(W[idx]);
    }
}

// ---- fused 4-matrix GEMM + elementwise epilogue ----
// xb: [T,K] bf16 row-major.  wt: [4][512][K] bf16 (slot s: 0=in,1=B,2=C,3=d), n-major.
// Writes a_bar, bx, C (fp32 [T,H]).
__global__ __launch_bounds__(256) void gemm_layer_kernel(
    const unsigned short* __restrict__ xb,
    const unsigned short* __restrict__ wt,
    const float* __restrict__ A_log,
    float* __restrict__ a_bar, float* __restrict__ bxo, float* __restrict__ Cc,
    int K)
{
    const int wave = threadIdx.x >> 6;
    const int lane = threadIdx.x & 63;
    const int ml   = lane & 15;
    const int quad = lane >> 4;
    const int m0   = blockIdx.x * 256 + wave * 64;
    const int n    = blockIdx.y * 16 + ml;

    const short8* pa[4];
    const short8* pb[4];
    #pragma unroll
    for (int i = 0; i < 4; i++)
        pa[i] = ((const short8*)xb) + ((size_t)(m0 + i * 16 + ml) * K) / 8 + quad;
    #pragma unroll
    for (int s = 0; s < 4; s++)
        pb[s] = ((const short8*)wt) + ((size_t)((s << 9) + n) * K) / 8 + quad;

    floatx4 acc[4][4];
    #pragma unroll
    for (int i = 0; i < 4; i++)
        #pragma unroll
        for (int s = 0; s < 4; s++)
            acc[i][s] = (floatx4)(0.0f);

    const int ksteps = K >> 5;        // K/32
    for (int kk = 0; kk < ksteps; ++kk){
        short8 av[4], bv[4];
        #pragma unroll
        for (int i = 0; i < 4; i++) av[i] = pa[i][kk * 4];
        #pragma unroll
        for (int s = 0; s < 4; s++) bv[s] = pb[s][kk * 4];
        #pragma unroll
        for (int i = 0; i < 4; i++)
            #pragma unroll
            for (int s = 0; s < 4; s++)
                acc[i][s] = __builtin_amdgcn_mfma_f32_16x16x32_bf16(av[i], bv[s], acc[i][s], 0, 0, 0);
    }

    const float Aneg = -expf(A_log[n]);

    #pragma unroll
    for (int i = 0; i < 4; i++){
        #pragma unroll
        for (int r = 0; r < 4; r++){
            int t = m0 + i * 16 + quad * 4 + r;     // C/D: row = quad*4 + reg
            size_t off = (size_t)t * H + n;          // col = lane&15
            float xs = acc[i][0][r];
            float Bv = acc[i][1][r];
            float Cv = acc[i][2][r];
            float dv = acc[i][3][r];
            float delta = 1.0f / (1.0f + expf(-dv));
            a_bar[off] = expf(delta * Aneg);
            bxo[off]   = Bv * xs;
            Cc[off]    = Cv;
        }
    }
}

// ---- scan pass 1: per-chunk aggregates (P = prod a, Hc = local scan end) ----
__global__ void scan1_kernel(const float* __restrict__ a, const float* __restrict__ bx,
                             float* __restrict__ P, float* __restrict__ Hc){
    int idx = blockIdx.x * 256 + threadIdx.x;
    int j = idx & (H - 1);
    int c = idx >> 9;
    size_t off = (size_t)c * CHUNK * H + j;
    float p = 1.0f, h = 0.0f;
    #pragma unroll 4
    for (int i = 0; i < CHUNK; i++){
        float av = a[off], b = bx[off];
        h = fmaf(av, h, b);
        p *= av;
        off += H;
    }
    P[(size_t)c * H + j]  = p;
    Hc[(size_t)c * H + j] = h;
}

// ---- scan pass 2: sequential cross-chunk combine (1 block, 512 threads) ----
__global__ void scan2_kernel(const float* __restrict__ P, const float* __restrict__ Hc,
                             float* __restrict__ S){
    const int j = threadIdx.x;
    float carry = 0.0f;
    for (int c0 = 0; c0 < NC; c0 += 8){
        float p[8], h[8];
        #pragma unroll
        for (int i = 0; i < 8; i++){
            p[i] = P[(size_t)(c0 + i) * H + j];
            h[i] = Hc[(size_t)(c0 + i) * H + j];
        }
        #pragma unroll
        for (int i = 0; i < 8; i++){
            S[(size_t)(c0 + i) * H + j] = carry;
            carry = fmaf(p[i], carry, h[i]);
        }
    }
}

// ---- scan pass 3 (layer 0): re-apply with start state, write y as bf16 for next GEMM ----
__global__ void scan3_bf16_kernel(const float* __restrict__ a, const float* __restrict__ bx,
                                  const float* __restrict__ Cc, const float* __restrict__ S,
                                  unsigned short* __restrict__ yb){
    int idx = blockIdx.x * 256 + threadIdx.x;
    int j = idx & (H - 1);
    int c = idx >> 9;
    float h = S[(size_t)c * H + j];
    size_t off = (size_t)c * CHUNK * H + j;
    #pragma unroll 4
    for (int i = 0; i < CHUNK; i++){
        h = fmaf(a[off], h, bx[off]);
        yb[off] = f2bf(Cc[off] * h);
        off += H;
    }
}

// ---- scan pass 3 (layer 1): write y2 fp32 (in-place over Cc is safe: same-thread RMW) ----
__global__ void scan3_f32_kernel(const float* __restrict__ a, const float* __restrict__ bx,
                                 const float* Cc, const float* __restrict__ S,
                                 float* y2){
    int idx = blockIdx.x * 256 + threadIdx.x;
    int j = idx & (H - 1);
    int c = idx >> 9;
    float h = S[(size_t)c * H + j];
    size_t off = (size_t)c * CHUNK * H + j;
    #pragma unroll 4
    for (int i = 0; i < CHUNK; i++){
        h = fmaf(a[off], h, bx[off]);
        y2[off] = Cc[off] * h;
        off += H;
    }
}

// ---- final: out[t][0:4] = y2[t]@W_out + b_out + x[t]@W_skip  (fp32, wave per row) ----
__global__ __launch_bounds__(256) void final_kernel(const float* __restrict__ y2,
                                                    const float* __restrict__ x,
                                                    const float* __restrict__ Wout,
                                                    const float* __restrict__ bout,
                                                    const float* __restrict__ Wskip,
                                                    float* __restrict__ out){
    int wave = threadIdx.x >> 6;
    int lane = threadIdx.x & 63;
    int t = blockIdx.x * 4 + wave;
    float s0 = 0.f, s1 = 0.f, s2 = 0.f, s3 = 0.f;
    const float4* W4 = (const float4*)Wout;
    #pragma unroll
    for (int k = lane; k < H; k += 64){
        float yv = y2[(size_t)t * H + k];
        float4 w = W4[k];
        s0 = fmaf(yv, w.x, s0); s1 = fmaf(yv, w.y, s1);
        s2 = fmaf(yv, w.z, s2); s3 = fmaf(yv, w.w, s3);
    }
    const float4* S4 = (const float4*)Wskip;
    #pragma unroll
    for (int k = lane; k < OBS; k += 64){
        float xv = x[(size_t)t * OBS + k];
        float4 w = S4[k];
        s0 = fmaf(xv, w.x, s0); s1 = fmaf(xv, w.y, s1);
        s2 = fmaf(xv, w.z, s2); s3 = fmaf(xv, w.w, s3);
    }
    #pragma unroll
    for (int off = 32; off > 0; off >>= 1){
        s0 += __shfl_down(s0, off);
        s1 += __shfl_down(s1, off);
        s2 += __shfl_down(s2, off);
        s3 += __shfl_down(s3, off);
    }
    if (lane == 0){
        out[(size_t)t * 4 + 0] = s0 + bout[0];
        out[(size_t)t * 4 + 1] = s1 + bout[1];
        out[(size_t)t * 4 + 2] = s2 + bout[2];
        out[(size_t)t * 4 + 3] = s3 + bout[3];
    }
}

extern "C" void kernel_launch(void* const* d_in, const int* in_sizes, int n_in,
                              void* d_out, int out_size, void* d_ws, size_t ws_size,
                              hipStream_t stream)
{
    const float* x     = (const float*)d_in[0];
    const float* W_in0 = (const float*)d_in[1];
    const float* W_B0  = (const float*)d_in[2];
    const float* W_C0  = (const float*)d_in[3];
    const float* W_d0  = (const float*)d_in[4];
    const float* A0    = (const float*)d_in[5];
    const float* W_in1 = (const float*)d_in[6];
    const float* W_B1  = (const float*)d_in[7];
    const float* W_C1  = (const float*)d_in[8];
    const float* W_d1  = (const float*)d_in[9];
    const float* A1    = (const float*)d_in[10];
    const float* Wout  = (const float*)d_in[11];
    const float* bout  = (const float*)d_in[12];
    const float* Wskip = (const float*)d_in[13];
    float* out = (float*)d_out;

    char* ws = (char*)d_ws;
    size_t off = 0;
    auto alloc = [&](size_t bytes) -> void* {
        void* p = ws + off;
        off += (bytes + 255) & ~(size_t)255;
        return p;
    };
    unsigned short* xb  = (unsigned short*)alloc((size_t)T_SIZE * OBS * 2);
    unsigned short* yb  = (unsigned short*)alloc((size_t)T_SIZE * H * 2);
    unsigned short* Wt0 = (unsigned short*)alloc((size_t)4 * H * OBS * 2);
    unsigned short* Wt1 = (unsigned short*)alloc((size_t)4 * H * H * 2);
    float* a_bar = (float*)alloc((size_t)T_SIZE * H * 4);
    float* bx    = (float*)alloc((size_t)T_SIZE * H * 4);
    float* Cc    = (float*)alloc((size_t)T_SIZE * H * 4);
    float* Pbuf  = (float*)alloc((size_t)NC * H * 4);
    float* Hbuf  = (float*)alloc((size_t)NC * H * 4);
    float* Sbuf  = (float*)alloc((size_t)NC * H * 4);
    (void)ws_size; (void)in_sizes; (void)n_in; (void)out_size;

    // ---- precision casts / weight transposes ----
    cast_x_kernel<<<(T_SIZE * OBS / 4 + 255) / 256, 256, 0, stream>>>(x, xb, T_SIZE * OBS / 4);
    {
        int n0 = OBS * H, g0 = (n0 + 255) / 256;
        tcast_kernel<<<g0, 256, 0, stream>>>(W_in0, Wt0 + (size_t)0 * H * OBS, OBS);
        tcast_kernel<<<g0, 256, 0, stream>>>(W_B0,  Wt0 + (size_t)1 * H * OBS, OBS);
        tcast_kernel<<<g0, 256, 0, stream>>>(W_C0,  Wt0 + (size_t)2 * H * OBS, OBS);
        tcast_kernel<<<g0, 256, 0, stream>>>(W_d0,  Wt0 + (size_t)3 * H * OBS, OBS);
        int n1 = H * H, g1 = (n1 + 255) / 256;
        tcast_kernel<<<g1, 256, 0, stream>>>(W_in1, Wt1 + (size_t)0 * H * H, H);
        tcast_kernel<<<g1, 256, 0, stream>>>(W_B1,  Wt1 + (size_t)1 * H * H, H);
        tcast_kernel<<<g1, 256, 0, stream>>>(W_C1,  Wt1 + (size_t)2 * H * H, H);
        tcast_kernel<<<g1, 256, 0, stream>>>(W_d1,  Wt1 + (size_t)3 * H * H, H);
    }

    dim3 ggrid(T_SIZE / 256, H / 16);
    const int sgrid = NC * H / 256;

    // ---- layer 0 ----
    gemm_layer_kernel<<<ggrid, 256, 0, stream>>>(xb, Wt0, A0, a_bar, bx, Cc, OBS);
    scan1_kernel<<<sgrid, 256, 0, stream>>>(a_bar, bx, Pbuf, Hbuf);
    scan2_kernel<<<1, H, 0, stream>>>(Pbuf, Hbuf, Sbuf);
    scan3_bf16_kernel<<<sgrid, 256, 0, stream>>>(a_bar, bx, Cc, Sbuf, yb);

    // ---- layer 1 ----
    gemm_layer_kernel<<<ggrid, 256, 0, stream>>>(yb, Wt1, A1, a_bar, bx, Cc, H);
    scan1_kernel<<<sgrid, 256, 0, stream>>>(a_bar, bx, Pbuf, Hbuf);
    scan2_kernel<<<1, H, 0, stream>>>(Pbuf, Hbuf, Sbuf);
    scan3_f32_kernel<<<sgrid, 256, 0, stream>>>(a_bar, bx, Cc, Sbuf, Cc /*in-place*/);

    // ---- output head ----
    final_kernel<<<T_SIZE / 4, 256, 0, stream>>>(Cc, x, Wout, bout, Wskip, out);
}

// Round 2
// 509.853 us; speedup vs baseline: 1.3880x; 1.3880x over previous
//
#include <hip/hip_runtime.h>

typedef __attribute__((ext_vector_type(8))) short short8;
typedef __attribute__((ext_vector_type(4))) float floatx4;

#define T_SIZE 32768
#define OBS    256
#define H      512
#define NC     512     // scan chunks
#define CHUNK  64      // T_SIZE / NC

__device__ __forceinline__ unsigned short f2bf(float f){
    union { float f; unsigned u; } v; v.f = f;
    unsigned u = v.u;
    u += 0x7FFFu + ((u >> 16) & 1u);   // round-to-nearest-even
    return (unsigned short)(u >> 16);
}

// async global->LDS, 16B per lane; lds base must be wave-uniform (HW adds lane*16)
#define GLOAD_LDS16(g, l) \
    __builtin_amdgcn_global_load_lds((const __attribute__((address_space(1))) unsigned*)(g), \
                                     (__attribute__((address_space(3))) unsigned*)(l), 16, 0, 0)

// ---- cast x [T,OBS] fp32 -> bf16, vectorized ----
__global__ void cast_x_kernel(const float* __restrict__ x, unsigned short* __restrict__ xb, int n4){
    int i = blockIdx.x * 256 + threadIdx.x;
    if (i < n4){
        float4 v = ((const float4*)x)[i];
        ushort4 o;
        o.x = f2bf(v.x); o.y = f2bf(v.y); o.z = f2bf(v.z); o.w = f2bf(v.w);
        ((ushort4*)xb)[i] = o;
    }
}

// ---- transpose+cast 4 weights W[K][512] fp32 -> interleaved [h/16][slot][16h][K] bf16 ----
__global__ void tcast4_kernel(const float* __restrict__ W0, const float* __restrict__ W1,
                              const float* __restrict__ W2, const float* __restrict__ W3,
                              unsigned short* __restrict__ dst, int K, int KH){
    int idx = blockIdx.x * 256 + threadIdx.x;
    if (idx >= 4 * KH) return;
    int s   = idx / KH;
    int rem = idx - s * KH;
    int k = rem >> 9;            // H == 512
    int h = rem & 511;
    const float* W = (s == 0) ? W0 : (s == 1) ? W1 : (s == 2) ? W2 : W3;
    int b = h >> 4, hh = h & 15;
    dst[(size_t)((b * 4 + s) * 16 + hh) * K + k] = f2bf(W[(size_t)k * H + h]);
}

// ---- fused 4-matrix GEMM (m97 structure) + elementwise epilogue ----
// xb: [T][K] bf16.  wt: [H/16][4 slots][16 h][K] bf16 (slot: 0=in,1=B,2=C,3=d).
// Block: 128 t  x  (32 h x 4 slots).  4 waves: (wm,wn) in 2x2.
// Wave: 64 t x (16 h x 4 slots) -> 4x4 grid of 16x16x32 MFMAs.
__global__ __launch_bounds__(256) void gemm_layer_kernel(
    const unsigned short* __restrict__ xb,
    const unsigned short* __restrict__ wt,
    const float* __restrict__ A_log,
    float* __restrict__ a_bar, float* __restrict__ bxo, float* __restrict__ Cc,
    int K)
{
    __shared__ unsigned short Asm[128 * 32];   // [row t][32 k]
    __shared__ unsigned short Bsm[128 * 32];   // [vcol = wn*64+slot*16+hh][32 k]

    const int tid  = threadIdx.x;
    const int wave = tid >> 6;
    const int lane = tid & 63;
    const int ml   = lane & 15;
    const int quad = lane >> 4;
    const int wm   = wave & 1;
    const int wn   = wave >> 1;
    const int nb   = blockIdx.x;            // 0..15 : h block of 32
    const int m0   = blockIdx.y * 128;      // t base

    const unsigned short* gA = xb + (size_t)m0 * K;
    const unsigned short* gB = wt + (size_t)nb * 128 * K;

    // staging: thread stages 2 x 16B for A and 2 x 16B for B per K-step
    const int srow = tid >> 2;              // 0..63 (+64 for chunk 1)
    const int selm = (tid & 3) * 8;         // element offset within 32-k slice

    floatx4 acc[4][4];
    #pragma unroll
    for (int i = 0; i < 4; i++)
        #pragma unroll
        for (int j = 0; j < 4; j++)
            acc[i][j] = (floatx4)(0.0f);

    for (int k0 = 0; k0 < K; k0 += 32){
        // ---- stage A[128][32], B[128][32] via async global->LDS ----
        GLOAD_LDS16(gA + (size_t)(srow      ) * K + k0 + selm, Asm + (size_t)(wave * 64 + 0  ) * 8);
        GLOAD_LDS16(gA + (size_t)(srow + 64 ) * K + k0 + selm, Asm + (size_t)(wave * 64 + 256) * 8);
        GLOAD_LDS16(gB + (size_t)(srow      ) * K + k0 + selm, Bsm + (size_t)(wave * 64 + 0  ) * 8);
        GLOAD_LDS16(gB + (size_t)(srow + 64 ) * K + k0 + selm, Bsm + (size_t)(wave * 64 + 256) * 8);
        __syncthreads();

        short8 av[4], bv[4];
        #pragma unroll
        for (int i = 0; i < 4; i++)
            av[i] = *(const short8*)(Asm + (size_t)(wm * 64 + i * 16 + ml) * 32 + quad * 8);
        #pragma unroll
        for (int j = 0; j < 4; j++)
            bv[j] = *(const short8*)(Bsm + (size_t)(wn * 64 + j * 16 + ml) * 32 + quad * 8);

        #pragma unroll
        for (int i = 0; i < 4; i++)
            #pragma unroll
            for (int j = 0; j < 4; j++)
                acc[i][j] = __builtin_amdgcn_mfma_f32_16x16x32_bf16(av[i], bv[j], acc[i][j], 0, 0, 0);
        __syncthreads();
    }

    // ---- epilogue: slot j: 0=x_state, 1=B, 2=C, 3=d ----
    const int h = nb * 32 + wn * 16 + ml;
    const float Aneg = -expf(A_log[h]);

    #pragma unroll
    for (int i = 0; i < 4; i++){
        #pragma unroll
        for (int r = 0; r < 4; r++){
            int t = m0 + wm * 64 + i * 16 + quad * 4 + r;   // C/D: row = quad*4 + reg
            size_t off = (size_t)t * H + h;
            float xs = acc[i][0][r];
            float Bv = acc[i][1][r];
            float Cv = acc[i][2][r];
            float dv = acc[i][3][r];
            float delta = 1.0f / (1.0f + expf(-dv));
            a_bar[off] = expf(delta * Aneg);
            bxo[off]   = Bv * xs;
            Cc[off]    = Cv;
        }
    }
}

// ---- scan pass 1: per-chunk aggregates (P = prod a, Hc = local scan end) ----
__global__ void scan1_kernel(const float* __restrict__ a, const float* __restrict__ bx,
                             float* __restrict__ P, float* __restrict__ Hc){
    int idx = blockIdx.x * 256 + threadIdx.x;
    int j = idx & (H - 1);
    int c = idx >> 9;
    size_t off = (size_t)c * CHUNK * H + j;
    float p = 1.0f, h = 0.0f;
    #pragma unroll 4
    for (int i = 0; i < CHUNK; i++){
        float av = a[off], b = bx[off];
        h = fmaf(av, h, b);
        p *= av;
        off += H;
    }
    P[(size_t)c * H + j]  = p;
    Hc[(size_t)c * H + j] = h;
}

// ---- scan pass 2: sequential cross-chunk combine (1 block, 512 threads) ----
__global__ void scan2_kernel(const float* __restrict__ P, const float* __restrict__ Hc,
                             float* __restrict__ S){
    const int j = threadIdx.x;
    float carry = 0.0f;
    for (int c0 = 0; c0 < NC; c0 += 8){
        float p[8], h[8];
        #pragma unroll
        for (int i = 0; i < 8; i++){
            p[i] = P[(size_t)(c0 + i) * H + j];
            h[i] = Hc[(size_t)(c0 + i) * H + j];
        }
        #pragma unroll
        for (int i = 0; i < 8; i++){
            S[(size_t)(c0 + i) * H + j] = carry;
            carry = fmaf(p[i], carry, h[i]);
        }
    }
}

// ---- scan pass 3 (layer 0): re-apply with start state, write y as bf16 for next GEMM ----
__global__ void scan3_bf16_kernel(const float* __restrict__ a, const float* __restrict__ bx,
                                  const float* __restrict__ Cc, const float* __restrict__ S,
                                  unsigned short* __restrict__ yb){
    int idx = blockIdx.x * 256 + threadIdx.x;
    int j = idx & (H - 1);
    int c = idx >> 9;
    float h = S[(size_t)c * H + j];
    size_t off = (size_t)c * CHUNK * H + j;
    #pragma unroll 4
    for (int i = 0; i < CHUNK; i++){
        h = fmaf(a[off], h, bx[off]);
        yb[off] = f2bf(Cc[off] * h);
        off += H;
    }
}

// ---- scan pass 3 (layer 1): write y2 fp32 (in-place over Cc is safe: same-thread RMW) ----
__global__ void scan3_f32_kernel(const float* __restrict__ a, const float* __restrict__ bx,
                                 const float* Cc, const float* __restrict__ S,
                                 float* y2){
    int idx = blockIdx.x * 256 + threadIdx.x;
    int j = idx & (H - 1);
    int c = idx >> 9;
    float h = S[(size_t)c * H + j];
    size_t off = (size_t)c * CHUNK * H + j;
    #pragma unroll 4
    for (int i = 0; i < CHUNK; i++){
        h = fmaf(a[off], h, bx[off]);
        y2[off] = Cc[off] * h;
        off += H;
    }
}

// ---- final: out[t][0:4] = y2[t]@W_out + b_out + x[t]@W_skip  (fp32, wave per row) ----
__global__ __launch_bounds__(256) void final_kernel(const float* __restrict__ y2,
                                                    const float* __restrict__ x,
                                                    const float* __restrict__ Wout,
                                                    const float* __restrict__ bout,
                                                    const float* __restrict__ Wskip,
                                                    float* __restrict__ out){
    int wave = threadIdx.x >> 6;
    int lane = threadIdx.x & 63;
    int t = blockIdx.x * 4 + wave;
    float s0 = 0.f, s1 = 0.f, s2 = 0.f, s3 = 0.f;
    const float4* W4 = (const float4*)Wout;
    #pragma unroll
    for (int k = lane; k < H; k += 64){
        float yv = y2[(size_t)t * H + k];
        float4 w = W4[k];
        s0 = fmaf(yv, w.x, s0); s1 = fmaf(yv, w.y, s1);
        s2 = fmaf(yv, w.z, s2); s3 = fmaf(yv, w.w, s3);
    }
    const float4* S4 = (const float4*)Wskip;
    #pragma unroll
    for (int k = lane; k < OBS; k += 64){
        float xv = x[(size_t)t * OBS + k];
        float4 w = S4[k];
        s0 = fmaf(xv, w.x, s0); s1 = fmaf(xv, w.y, s1);
        s2 = fmaf(xv, w.z, s2); s3 = fmaf(xv, w.w, s3);
    }
    #pragma unroll
    for (int off = 32; off > 0; off >>= 1){
        s0 += __shfl_down(s0, off);
        s1 += __shfl_down(s1, off);
        s2 += __shfl_down(s2, off);
        s3 += __shfl_down(s3, off);
    }
    if (lane == 0){
        out[(size_t)t * 4 + 0] = s0 + bout[0];
        out[(size_t)t * 4 + 1] = s1 + bout[1];
        out[(size_t)t * 4 + 2] = s2 + bout[2];
        out[(size_t)t * 4 + 3] = s3 + bout[3];
    }
}

extern "C" void kernel_launch(void* const* d_in, const int* in_sizes, int n_in,
                              void* d_out, int out_size, void* d_ws, size_t ws_size,
                              hipStream_t stream)
{
    const float* x     = (const float*)d_in[0];
    const float* W_in0 = (const float*)d_in[1];
    const float* W_B0  = (const float*)d_in[2];
    const float* W_C0  = (const float*)d_in[3];
    const float* W_d0  = (const float*)d_in[4];
    const float* A0    = (const float*)d_in[5];
    const float* W_in1 = (const float*)d_in[6];
    const float* W_B1  = (const float*)d_in[7];
    const float* W_C1  = (const float*)d_in[8];
    const float* W_d1  = (const float*)d_in[9];
    const float* A1    = (const float*)d_in[10];
    const float* Wout  = (const float*)d_in[11];
    const float* bout  = (const float*)d_in[12];
    const float* Wskip = (const float*)d_in[13];
    float* out = (float*)d_out;

    char* ws = (char*)d_ws;
    size_t off = 0;
    auto alloc = [&](size_t bytes) -> void* {
        void* p = ws + off;
        off += (bytes + 255) & ~(size_t)255;
        return p;
    };
    unsigned short* xb  = (unsigned short*)alloc((size_t)T_SIZE * OBS * 2);
    unsigned short* yb  = (unsigned short*)alloc((size_t)T_SIZE * H * 2);
    unsigned short* Wt0 = (unsigned short*)alloc((size_t)4 * H * OBS * 2);
    unsigned short* Wt1 = (unsigned short*)alloc((size_t)4 * H * H * 2);
    float* a_bar = (float*)alloc((size_t)T_SIZE * H * 4);
    float* bx    = (float*)alloc((size_t)T_SIZE * H * 4);
    float* Cc    = (float*)alloc((size_t)T_SIZE * H * 4);
    float* Pbuf  = (float*)alloc((size_t)NC * H * 4);
    float* Hbuf  = (float*)alloc((size_t)NC * H * 4);
    float* Sbuf  = (float*)alloc((size_t)NC * H * 4);
    (void)ws_size; (void)in_sizes; (void)n_in; (void)out_size;

    // ---- precision casts / weight transposes (interleaved layout) ----
    cast_x_kernel<<<(T_SIZE * OBS / 4 + 255) / 256, 256, 0, stream>>>(x, xb, T_SIZE * OBS / 4);
    tcast4_kernel<<<(4 * OBS * H + 255) / 256, 256, 0, stream>>>(W_in0, W_B0, W_C0, W_d0, Wt0, OBS, OBS * H);
    tcast4_kernel<<<(4 * H   * H + 255) / 256, 256, 0, stream>>>(W_in1, W_B1, W_C1, W_d1, Wt1, H,   H * H);

    dim3 ggrid(H / 32, T_SIZE / 128);   // nb fastest: 16 consecutive blocks share one A-panel
    const int sgrid = NC * H / 256;

    // ---- layer 0 ----
    gemm_layer_kernel<<<ggrid, 256, 0, stream>>>(xb, Wt0, A0, a_bar, bx, Cc, OBS);
    scan1_kernel<<<sgrid, 256, 0, stream>>>(a_bar, bx, Pbuf, Hbuf);
    scan2_kernel<<<1, H, 0, stream>>>(Pbuf, Hbuf, Sbuf);
    scan3_bf16_kernel<<<sgrid, 256, 0, stream>>>(a_bar, bx, Cc, Sbuf, yb);

    // ---- layer 1 ----
    gemm_layer_kernel<<<ggrid, 256, 0, stream>>>(yb, Wt1, A1, a_bar, bx, Cc, H);
    scan1_kernel<<<sgrid, 256, 0, stream>>>(a_bar, bx, Pbuf, Hbuf);
    scan2_kernel<<<1, H, 0, stream>>>(Pbuf, Hbuf, Sbuf);
    scan3_f32_kernel<<<sgrid, 256, 0, stream>>>(a_bar, bx, Cc, Sbuf, Cc /*in-place*/);

    // ---- output head ----
    final_kernel<<<T_SIZE / 4, 256, 0, stream>>>(Cc, x, Wout, bout, Wskip, out);
}

// Round 3
// 474.468 us; speedup vs baseline: 1.4915x; 1.0746x over previous
//
#include <hip/hip_runtime.h>

typedef __attribute__((ext_vector_type(8))) short short8;
typedef __attribute__((ext_vector_type(4))) float floatx4;

#define T_SIZE 32768
#define OBS    256
#define H      512
#define NC     512     // scan chunks
#define CHUNK  64      // T_SIZE / NC

__device__ __forceinline__ unsigned short f2bf(float f){
    union { float f; unsigned u; } v; v.f = f;
    unsigned u = v.u;
    u += 0x7FFFu + ((u >> 16) & 1u);   // round-to-nearest-even
    return (unsigned short)(u >> 16);
}
__device__ __forceinline__ float bf2f(unsigned short u){
    union { unsigned u; float f; } v; v.u = ((unsigned)u) << 16; return v.f;
}

// async global->LDS, 16B per lane; lds base must be wave-uniform (HW adds lane*16)
#define GLOAD_LDS16(g, l) \
    __builtin_amdgcn_global_load_lds((const __attribute__((address_space(1))) unsigned*)(g), \
                                     (__attribute__((address_space(3))) unsigned*)(l), 16, 0, 0)

// ---- cast x [T,OBS] fp32 -> bf16, vectorized ----
__global__ void cast_x_kernel(const float* __restrict__ x, unsigned short* __restrict__ xb, int n4){
    int i = blockIdx.x * 256 + threadIdx.x;
    if (i < n4){
        float4 v = ((const float4*)x)[i];
        ushort4 o;
        o.x = f2bf(v.x); o.y = f2bf(v.y); o.z = f2bf(v.z); o.w = f2bf(v.w);
        ((ushort4*)xb)[i] = o;
    }
}

// ---- transpose+cast 4 weights W[K][512] fp32 -> interleaved [h/16][slot][16h][K] bf16 ----
__global__ void tcast4_kernel(const float* __restrict__ W0, const float* __restrict__ W1,
                              const float* __restrict__ W2, const float* __restrict__ W3,
                              unsigned short* __restrict__ dst, int K, int KH){
    int idx = blockIdx.x * 256 + threadIdx.x;
    if (idx >= 4 * KH) return;
    int s   = idx / KH;
    int rem = idx - s * KH;
    int k = rem >> 9;            // H == 512
    int h = rem & 511;
    const float* W = (s == 0) ? W0 : (s == 1) ? W1 : (s == 2) ? W2 : W3;
    int b = h >> 4, hh = h & 15;
    dst[(size_t)((b * 4 + s) * 16 + hh) * K + k] = f2bf(W[(size_t)k * H + h]);
}

// ---- fused 4-matrix GEMM (m97 structure, XOR-swizzled LDS) + elementwise epilogue ----
// xb: [T][K] bf16.  wt: [H/16][4 slots][16 h][K] bf16 (slot: 0=in,1=B,2=C,3=d).
// Block: 128 t  x  (32 h x 4 slots).  4 waves: (wm,wn) in 2x2.
// LDS row = 32 k = 4 chunks of 16B; chunk c of row r stored at position c ^ ((r>>1)&3).
__global__ __launch_bounds__(256) void gemm_layer_kernel(
    const unsigned short* __restrict__ xb,
    const unsigned short* __restrict__ wt,
    const float* __restrict__ A_log,
    float* __restrict__ a_bar, unsigned short* __restrict__ bxo, unsigned short* __restrict__ Cc,
    int K)
{
    __shared__ unsigned short Asm[128 * 32];   // [row t][32 k] swizzled
    __shared__ unsigned short Bsm[128 * 32];   // [vcol][32 k] swizzled

    const int tid  = threadIdx.x;
    const int wave = tid >> 6;
    const int lane = tid & 63;
    const int ml   = lane & 15;
    const int quad = lane >> 4;
    const int wm   = wave & 1;
    const int wn   = wave >> 1;
    const int nb   = blockIdx.x;            // 0..15 : h block of 32
    const int m0   = blockIdx.y * 128;      // t base

    const unsigned short* gA = xb + (size_t)m0 * K;
    const unsigned short* gB = wt + (size_t)nb * 128 * K;

    // staging: LDS row r = wave*16 + (lane>>2) (+64), chunk position c' = lane&3.
    // source global chunk = c' ^ ((r>>1)&3) = (tid&3) ^ ((tid>>3)&3)   (wave terms vanish mod 4)
    const int srow = tid >> 2;
    const int sel  = (((tid & 3) ^ ((tid >> 3) & 3))) * 8;

    // read-side swizzle: rows i*16+ml (+wm*64 etc., all ≡0 mod 4 except ml): (r>>1)&3 = (ml>>1)&3
    const int swz = (ml >> 1) & 3;

    floatx4 acc[4][4];
    #pragma unroll
    for (int i = 0; i < 4; i++)
        #pragma unroll
        for (int j = 0; j < 4; j++)
            acc[i][j] = (floatx4)(0.0f);

    for (int k0 = 0; k0 < K; k0 += 32){
        GLOAD_LDS16(gA + (size_t)(srow      ) * K + k0 + sel, Asm + (size_t)(wave * 64 + 0  ) * 8);
        GLOAD_LDS16(gA + (size_t)(srow + 64 ) * K + k0 + sel, Asm + (size_t)(wave * 64 + 256) * 8);
        GLOAD_LDS16(gB + (size_t)(srow      ) * K + k0 + sel, Bsm + (size_t)(wave * 64 + 0  ) * 8);
        GLOAD_LDS16(gB + (size_t)(srow + 64 ) * K + k0 + sel, Bsm + (size_t)(wave * 64 + 256) * 8);
        __syncthreads();

        short8 av[4], bv[4];
        #pragma unroll
        for (int i = 0; i < 4; i++)
            av[i] = *(const short8*)(Asm + (size_t)(wm * 64 + i * 16 + ml) * 32 + (quad ^ swz) * 8);
        #pragma unroll
        for (int j = 0; j < 4; j++)
            bv[j] = *(const short8*)(Bsm + (size_t)(wn * 64 + j * 16 + ml) * 32 + (quad ^ swz) * 8);

        #pragma unroll
        for (int i = 0; i < 4; i++)
            #pragma unroll
            for (int j = 0; j < 4; j++)
                acc[i][j] = __builtin_amdgcn_mfma_f32_16x16x32_bf16(av[i], bv[j], acc[i][j], 0, 0, 0);
        __syncthreads();
    }

    // ---- epilogue: slot j: 0=x_state, 1=B, 2=C, 3=d ----
    const int h = nb * 32 + wn * 16 + ml;
    const float Aneg = -expf(A_log[h]);

    #pragma unroll
    for (int i = 0; i < 4; i++){
        #pragma unroll
        for (int r = 0; r < 4; r++){
            int t = m0 + wm * 64 + i * 16 + quad * 4 + r;   // C/D: row = quad*4 + reg
            size_t off = (size_t)t * H + h;
            float xs = acc[i][0][r];
            float Bv = acc[i][1][r];
            float Cv = acc[i][2][r];
            float dv = acc[i][3][r];
            float delta = 1.0f / (1.0f + expf(-dv));
            a_bar[off] = expf(delta * Aneg);
            bxo[off]   = f2bf(Bv * xs);
            Cc[off]    = f2bf(Cv);
        }
    }
}

// ---- scan pass 1: per-chunk aggregates; 4 channels/thread, vectorized ----
__global__ void scan1_kernel(const float* __restrict__ a, const unsigned short* __restrict__ bx,
                             float* __restrict__ P, float* __restrict__ Hc){
    int idx = blockIdx.x * 256 + threadIdx.x;     // NC * H/4
    int j4 = (idx & 127) * 4;
    int c  = idx >> 7;
    size_t off = (size_t)c * CHUNK * H + j4;
    float4 p = {1.f,1.f,1.f,1.f}, h = {0.f,0.f,0.f,0.f};
    #pragma unroll 4
    for (int i = 0; i < CHUNK; i++){
        float4 av  = *(const float4*)(a + off);
        ushort4 bv = *(const ushort4*)(bx + off);
        h.x = fmaf(av.x, h.x, bf2f(bv.x)); p.x *= av.x;
        h.y = fmaf(av.y, h.y, bf2f(bv.y)); p.y *= av.y;
        h.z = fmaf(av.z, h.z, bf2f(bv.z)); p.z *= av.z;
        h.w = fmaf(av.w, h.w, bf2f(bv.w)); p.w *= av.w;
        off += H;
    }
    *(float4*)(P  + (size_t)c * H + j4) = p;
    *(float4*)(Hc + (size_t)c * H + j4) = h;
}

// ---- scan pass 2: sequential cross-chunk combine (1 block, 512 threads) ----
__global__ void scan2_kernel(const float* __restrict__ P, const float* __restrict__ Hc,
                             float* __restrict__ S){
    const int j = threadIdx.x;
    float carry = 0.0f;
    for (int c0 = 0; c0 < NC; c0 += 8){
        float p[8], h[8];
        #pragma unroll
        for (int i = 0; i < 8; i++){
            p[i] = P[(size_t)(c0 + i) * H + j];
            h[i] = Hc[(size_t)(c0 + i) * H + j];
        }
        #pragma unroll
        for (int i = 0; i < 8; i++){
            S[(size_t)(c0 + i) * H + j] = carry;
            carry = fmaf(p[i], carry, h[i]);
        }
    }
}

// ---- scan pass 3 (layer 0): re-apply with start state, y -> bf16 for next GEMM ----
__global__ void scan3_bf16_kernel(const float* __restrict__ a, const unsigned short* __restrict__ bx,
                                  const unsigned short* __restrict__ Cc, const float* __restrict__ S,
                                  unsigned short* __restrict__ yb){
    int idx = blockIdx.x * 256 + threadIdx.x;
    int j4 = (idx & 127) * 4;
    int c  = idx >> 7;
    float4 h = *(const float4*)(S + (size_t)c * H + j4);
    size_t off = (size_t)c * CHUNK * H + j4;
    #pragma unroll 4
    for (int i = 0; i < CHUNK; i++){
        float4 av  = *(const float4*)(a + off);
        ushort4 bv = *(const ushort4*)(bx + off);
        ushort4 cv = *(const ushort4*)(Cc + off);
        h.x = fmaf(av.x, h.x, bf2f(bv.x));
        h.y = fmaf(av.y, h.y, bf2f(bv.y));
        h.z = fmaf(av.z, h.z, bf2f(bv.z));
        h.w = fmaf(av.w, h.w, bf2f(bv.w));
        ushort4 o;
        o.x = f2bf(bf2f(cv.x) * h.x);
        o.y = f2bf(bf2f(cv.y) * h.y);
        o.z = f2bf(bf2f(cv.z) * h.z);
        o.w = f2bf(bf2f(cv.w) * h.w);
        *(ushort4*)(yb + off) = o;
        off += H;
    }
}

// ---- scan pass 3 (layer 1): y2 fp32 written IN PLACE over a (same-thread RMW; no restrict) ----
__global__ void scan3_f32_kernel(const float* a, const unsigned short* __restrict__ bx,
                                 const unsigned short* __restrict__ Cc, const float* __restrict__ S,
                                 float* y2){
    int idx = blockIdx.x * 256 + threadIdx.x;
    int j4 = (idx & 127) * 4;
    int c  = idx >> 7;
    float4 h = *(const float4*)(S + (size_t)c * H + j4);
    size_t off = (size_t)c * CHUNK * H + j4;
    #pragma unroll 4
    for (int i = 0; i < CHUNK; i++){
        float4 av  = *(const float4*)(a + off);
        ushort4 bv = *(const ushort4*)(bx + off);
        ushort4 cv = *(const ushort4*)(Cc + off);
        h.x = fmaf(av.x, h.x, bf2f(bv.x));
        h.y = fmaf(av.y, h.y, bf2f(bv.y));
        h.z = fmaf(av.z, h.z, bf2f(bv.z));
        h.w = fmaf(av.w, h.w, bf2f(bv.w));
        float4 o;
        o.x = bf2f(cv.x) * h.x;
        o.y = bf2f(cv.y) * h.y;
        o.z = bf2f(cv.z) * h.z;
        o.w = bf2f(cv.w) * h.w;
        *(float4*)(y2 + off) = o;
        off += H;
    }
}

// ---- final: out[t][0:4] = y2[t]@W_out + b_out + x[t]@W_skip  (fp32, wave per row) ----
__global__ __launch_bounds__(256) void final_kernel(const float* __restrict__ y2,
                                                    const float* __restrict__ x,
                                                    const float* __restrict__ Wout,
                                                    const float* __restrict__ bout,
                                                    const float* __restrict__ Wskip,
                                                    float* __restrict__ out){
    int wave = threadIdx.x >> 6;
    int lane = threadIdx.x & 63;
    int t = blockIdx.x * 4 + wave;
    float s0 = 0.f, s1 = 0.f, s2 = 0.f, s3 = 0.f;
    const float4* W4 = (const float4*)Wout;
    #pragma unroll
    for (int k = lane; k < H; k += 64){
        float yv = y2[(size_t)t * H + k];
        float4 w = W4[k];
        s0 = fmaf(yv, w.x, s0); s1 = fmaf(yv, w.y, s1);
        s2 = fmaf(yv, w.z, s2); s3 = fmaf(yv, w.w, s3);
    }
    const float4* S4 = (const float4*)Wskip;
    #pragma unroll
    for (int k = lane; k < OBS; k += 64){
        float xv = x[(size_t)t * OBS + k];
        float4 w = S4[k];
        s0 = fmaf(xv, w.x, s0); s1 = fmaf(xv, w.y, s1);
        s2 = fmaf(xv, w.z, s2); s3 = fmaf(xv, w.w, s3);
    }
    #pragma unroll
    for (int off = 32; off > 0; off >>= 1){
        s0 += __shfl_down(s0, off);
        s1 += __shfl_down(s1, off);
        s2 += __shfl_down(s2, off);
        s3 += __shfl_down(s3, off);
    }
    if (lane == 0){
        out[(size_t)t * 4 + 0] = s0 + bout[0];
        out[(size_t)t * 4 + 1] = s1 + bout[1];
        out[(size_t)t * 4 + 2] = s2 + bout[2];
        out[(size_t)t * 4 + 3] = s3 + bout[3];
    }
}

extern "C" void kernel_launch(void* const* d_in, const int* in_sizes, int n_in,
                              void* d_out, int out_size, void* d_ws, size_t ws_size,
                              hipStream_t stream)
{
    const float* x     = (const float*)d_in[0];
    const float* W_in0 = (const float*)d_in[1];
    const float* W_B0  = (const float*)d_in[2];
    const float* W_C0  = (const float*)d_in[3];
    const float* W_d0  = (const float*)d_in[4];
    const float* A0    = (const float*)d_in[5];
    const float* W_in1 = (const float*)d_in[6];
    const float* W_B1  = (const float*)d_in[7];
    const float* W_C1  = (const float*)d_in[8];
    const float* W_d1  = (const float*)d_in[9];
    const float* A1    = (const float*)d_in[10];
    const float* Wout  = (const float*)d_in[11];
    const float* bout  = (const float*)d_in[12];
    const float* Wskip = (const float*)d_in[13];
    float* out = (float*)d_out;

    char* ws = (char*)d_ws;
    size_t off = 0;
    auto alloc = [&](size_t bytes) -> void* {
        void* p = ws + off;
        off += (bytes + 255) & ~(size_t)255;
        return p;
    };
    unsigned short* xb  = (unsigned short*)alloc((size_t)T_SIZE * OBS * 2);
    unsigned short* yb  = (unsigned short*)alloc((size_t)T_SIZE * H * 2);
    unsigned short* Wt0 = (unsigned short*)alloc((size_t)4 * H * OBS * 2);
    unsigned short* Wt1 = (unsigned short*)alloc((size_t)4 * H * H * 2);
    float*          a_bar = (float*)alloc((size_t)T_SIZE * H * 4);           // also y2 in place
    unsigned short* bx    = (unsigned short*)alloc((size_t)T_SIZE * H * 2);
    unsigned short* Cc    = (unsigned short*)alloc((size_t)T_SIZE * H * 2);
    float* Pbuf  = (float*)alloc((size_t)NC * H * 4);
    float* Hbuf  = (float*)alloc((size_t)NC * H * 4);
    float* Sbuf  = (float*)alloc((size_t)NC * H * 4);
    (void)ws_size; (void)in_sizes; (void)n_in; (void)out_size;

    // ---- precision casts / weight transposes (interleaved layout) ----
    cast_x_kernel<<<(T_SIZE * OBS / 4 + 255) / 256, 256, 0, stream>>>(x, xb, T_SIZE * OBS / 4);
    tcast4_kernel<<<(4 * OBS * H + 255) / 256, 256, 0, stream>>>(W_in0, W_B0, W_C0, W_d0, Wt0, OBS, OBS * H);
    tcast4_kernel<<<(4 * H   * H + 255) / 256, 256, 0, stream>>>(W_in1, W_B1, W_C1, W_d1, Wt1, H,   H * H);

    dim3 ggrid(H / 32, T_SIZE / 128);   // nb fastest: 16 consecutive blocks share one A-panel
    const int sgrid = NC * (H / 4) / 256;   // 256 blocks

    // ---- layer 0 ----
    gemm_layer_kernel<<<ggrid, 256, 0, stream>>>(xb, Wt0, A0, a_bar, bx, Cc, OBS);
    scan1_kernel<<<sgrid, 256, 0, stream>>>(a_bar, bx, Pbuf, Hbuf);
    scan2_kernel<<<1, H, 0, stream>>>(Pbuf, Hbuf, Sbuf);
    scan3_bf16_kernel<<<sgrid, 256, 0, stream>>>(a_bar, bx, Cc, Sbuf, yb);

    // ---- layer 1 ----
    gemm_layer_kernel<<<ggrid, 256, 0, stream>>>(yb, Wt1, A1, a_bar, bx, Cc, H);
    scan1_kernel<<<sgrid, 256, 0, stream>>>(a_bar, bx, Pbuf, Hbuf);
    scan2_kernel<<<1, H, 0, stream>>>(Pbuf, Hbuf, Sbuf);
    scan3_f32_kernel<<<sgrid, 256, 0, stream>>>(a_bar, bx, Cc, Sbuf, a_bar /*in place*/);

    // ---- output head ----
    final_kernel<<<T_SIZE / 4, 256, 0, stream>>>(a_bar, x, Wout, bout, Wskip, out);
}

// Round 4
// 419.040 us; speedup vs baseline: 1.6888x; 1.1323x over previous
//
#include <hip/hip_runtime.h>

typedef __attribute__((ext_vector_type(8))) short short8;
typedef __attribute__((ext_vector_type(4))) float floatx4;

#define T_SIZE 32768
#define OBS    256
#define H      512
#define NC     512     // scan chunks
#define CHUNK  64      // T_SIZE / NC
#define NGRP   32      // scan2 groups
#define GCH    16      // chunks per group
#define SLAB   ((size_t)T_SIZE * 32)   // one h-block slab in tiled layout

__device__ __forceinline__ unsigned short f2bf(float f){
    union { float f; unsigned u; } v; v.f = f;
    unsigned u = v.u;
    u += 0x7FFFu + ((u >> 16) & 1u);   // round-to-nearest-even
    return (unsigned short)(u >> 16);
}
__device__ __forceinline__ float bf2f(unsigned short u){
    union { unsigned u; float f; } v; v.u = ((unsigned)u) << 16; return v.f;
}

// async global->LDS, 16B per lane; lds base must be wave-uniform (HW adds lane*16)
#define GLOAD_LDS16(g, l) \
    __builtin_amdgcn_global_load_lds((const __attribute__((address_space(1))) unsigned*)(g), \
                                     (__attribute__((address_space(3))) unsigned*)(l), 16, 0, 0)

// ---- cast x [T,OBS] fp32 -> bf16, vectorized ----
__global__ void cast_x_kernel(const float* __restrict__ x, unsigned short* __restrict__ xb, int n4){
    int i = blockIdx.x * 256 + threadIdx.x;
    if (i < n4){
        float4 v = ((const float4*)x)[i];
        ushort4 o;
        o.x = f2bf(v.x); o.y = f2bf(v.y); o.z = f2bf(v.z); o.w = f2bf(v.w);
        ((ushort4*)xb)[i] = o;
    }
}

// ---- transpose+cast 4 weights W[K][512] fp32 -> interleaved [h/16][slot][16h][K] bf16 ----
__global__ void tcast4_kernel(const float* __restrict__ W0, const float* __restrict__ W1,
                              const float* __restrict__ W2, const float* __restrict__ W3,
                              unsigned short* __restrict__ dst, int K, int KH){
    int idx = blockIdx.x * 256 + threadIdx.x;
    if (idx >= 4 * KH) return;
    int s   = idx / KH;
    int rem = idx - s * KH;
    int k = rem >> 9;            // H == 512
    int h = rem & 511;
    const float* W = (s == 0) ? W0 : (s == 1) ? W1 : (s == 2) ? W2 : W3;
    int b = h >> 4, hh = h & 15;
    dst[(size_t)((b * 4 + s) * 16 + hh) * K + k] = f2bf(W[(size_t)k * H + h]);
}

// ---- fused 4-matrix GEMM (m97 structure, XOR-swizzled LDS) + tiled streaming epilogue ----
// xb: [T][K] bf16.  wt: [H/16][4 slots][16 h][K] bf16 (slot: 0=in,1=B,2=C,3=d).
// Outputs TILED: aT/bxT/CT are [H/32][T][32] (slab = T*32) so block writes are contiguous.
__global__ __launch_bounds__(256) void gemm_layer_kernel(
    const unsigned short* __restrict__ xb,
    const unsigned short* __restrict__ wt,
    const float* __restrict__ A_log,
    float* __restrict__ aT, unsigned short* __restrict__ bxT, unsigned short* __restrict__ CT,
    int K)
{
    __shared__ unsigned short SM[2 * 128 * 32];    // 16 KB: A panel | B panel, reused by epilogue
    unsigned short* Asm = SM;
    unsigned short* Bsm = SM + 128 * 32;

    const int tid  = threadIdx.x;
    const int wave = tid >> 6;
    const int lane = tid & 63;
    const int ml   = lane & 15;
    const int quad = lane >> 4;
    const int wm   = wave & 1;
    const int wn   = wave >> 1;
    const int nb   = blockIdx.x;            // 0..15 : h block of 32
    const int m0   = blockIdx.y * 128;      // t base

    const unsigned short* gA = xb + (size_t)m0 * K;
    const unsigned short* gB = wt + (size_t)nb * 128 * K;

    // staging: LDS row r = tid>>2 (+64), chunk position c' = tid&3; source chunk XOR-swizzled
    const int srow = tid >> 2;
    const int sel  = (((tid & 3) ^ ((tid >> 3) & 3))) * 8;
    const int swz  = (ml >> 1) & 3;         // read-side swizzle

    floatx4 acc[4][4];
    #pragma unroll
    for (int i = 0; i < 4; i++)
        #pragma unroll
        for (int j = 0; j < 4; j++)
            acc[i][j] = (floatx4)(0.0f);

    for (int k0 = 0; k0 < K; k0 += 32){
        GLOAD_LDS16(gA + (size_t)(srow      ) * K + k0 + sel, Asm + (size_t)(wave * 64 + 0  ) * 8);
        GLOAD_LDS16(gA + (size_t)(srow + 64 ) * K + k0 + sel, Asm + (size_t)(wave * 64 + 256) * 8);
        GLOAD_LDS16(gB + (size_t)(srow      ) * K + k0 + sel, Bsm + (size_t)(wave * 64 + 0  ) * 8);
        GLOAD_LDS16(gB + (size_t)(srow + 64 ) * K + k0 + sel, Bsm + (size_t)(wave * 64 + 256) * 8);
        __syncthreads();

        short8 av[4], bv[4];
        #pragma unroll
        for (int i = 0; i < 4; i++)
            av[i] = *(const short8*)(Asm + (size_t)(wm * 64 + i * 16 + ml) * 32 + (quad ^ swz) * 8);
        #pragma unroll
        for (int j = 0; j < 4; j++)
            bv[j] = *(const short8*)(Bsm + (size_t)(wn * 64 + j * 16 + ml) * 32 + (quad ^ swz) * 8);

        #pragma unroll
        for (int i = 0; i < 4; i++)
            #pragma unroll
            for (int j = 0; j < 4; j++)
                acc[i][j] = __builtin_amdgcn_mfma_f32_16x16x32_bf16(av[i], bv[j], acc[i][j], 0, 0, 0);
        __syncthreads();   // also guarantees LDS is free for epilogue reuse
    }

    // ---- epilogue: slots 0=x_state, 1=B, 2=C, 3=d.  Stage in LDS, stream out. ----
    const int col = wn * 16 + ml;            // 0..31 h within block
    const int h   = nb * 32 + col;
    const float Aneg = -expf(A_log[h]);

    // round 1: a_bar (fp32, 16 KB)
    float* smf = (float*)SM;
    #pragma unroll
    for (int i = 0; i < 4; i++){
        #pragma unroll
        for (int r = 0; r < 4; r++){
            int trow = wm * 64 + i * 16 + quad * 4 + r;
            float dv = acc[i][3][r];
            float delta = 1.0f / (1.0f + expf(-dv));
            smf[trow * 32 + col] = expf(delta * Aneg);
        }
    }
    __syncthreads();
    {
        const float4* src = (const float4*)smf;
        float4* dst = (float4*)(aT + (size_t)nb * SLAB + (size_t)m0 * 32);
        #pragma unroll
        for (int v = 0; v < 4; v++) dst[tid + v * 256] = src[tid + v * 256];
    }
    __syncthreads();

    // round 2: bx (bf16, 8 KB) + C (bf16, 8 KB)
    #pragma unroll
    for (int i = 0; i < 4; i++){
        #pragma unroll
        for (int r = 0; r < 4; r++){
            int trow = wm * 64 + i * 16 + quad * 4 + r;
            SM[trow * 32 + col]        = f2bf(acc[i][1][r] * acc[i][0][r]);   // B * x_state
            SM[4096 + trow * 32 + col] = f2bf(acc[i][2][r]);                  // C
        }
    }
    __syncthreads();
    {
        const short8* s8 = (const short8*)SM;
        short8* db = (short8*)(bxT + (size_t)nb * SLAB + (size_t)m0 * 32);
        short8* dc = (short8*)(CT  + (size_t)nb * SLAB + (size_t)m0 * 32);
        db[tid] = s8[tid];       db[tid + 256] = s8[tid + 256];
        dc[tid] = s8[512 + tid]; dc[tid + 256] = s8[768 + tid];
    }
}

// ---- scan pass 1: per-chunk aggregates from tiled inputs ----
__global__ void scan1_kernel(const float* __restrict__ aT, const unsigned short* __restrict__ bxT,
                             float* __restrict__ P, float* __restrict__ Hc){
    int idx = blockIdx.x * 256 + threadIdx.x;     // NC * 128
    int j4 = (idx & 127) * 4;
    int c  = idx >> 7;
    int nb = j4 >> 5, jj = j4 & 31;
    size_t off = (size_t)nb * SLAB + (size_t)c * CHUNK * 32 + jj;
    float4 p = {1.f,1.f,1.f,1.f}, h = {0.f,0.f,0.f,0.f};
    #pragma unroll 4
    for (int i = 0; i < CHUNK; i++){
        float4 av  = *(const float4*)(aT + off);
        ushort4 bv = *(const ushort4*)(bxT + off);
        h.x = fmaf(av.x, h.x, bf2f(bv.x)); p.x *= av.x;
        h.y = fmaf(av.y, h.y, bf2f(bv.y)); p.y *= av.y;
        h.z = fmaf(av.z, h.z, bf2f(bv.z)); p.z *= av.z;
        h.w = fmaf(av.w, h.w, bf2f(bv.w)); p.w *= av.w;
        off += 32;
    }
    *(float4*)(P  + (size_t)c * H + j4) = p;
    *(float4*)(Hc + (size_t)c * H + j4) = h;
}

// ---- scan pass 2a: 32 groups x 16 chunks, local exclusive prefix + group aggregate ----
__global__ void scan2a_kernel(const float* __restrict__ P, const float* __restrict__ Hc,
                              float* __restrict__ Sloc, float* __restrict__ Pp,
                              float* __restrict__ Pg, float* __restrict__ Hg){
    const int g  = blockIdx.x;          // 0..31
    const int j4 = threadIdx.x * 4;     // 128 threads
    float4 pc = {1.f,1.f,1.f,1.f}, hc = {0.f,0.f,0.f,0.f};
    #pragma unroll
    for (int i = 0; i < GCH; i++){
        size_t o = (size_t)(g * GCH + i) * H + j4;
        float4 P4 = *(const float4*)(P + o);
        float4 H4 = *(const float4*)(Hc + o);
        *(float4*)(Sloc + o) = hc;
        *(float4*)(Pp   + o) = pc;
        hc.x = fmaf(P4.x, hc.x, H4.x); pc.x *= P4.x;
        hc.y = fmaf(P4.y, hc.y, H4.y); pc.y *= P4.y;
        hc.z = fmaf(P4.z, hc.z, H4.z); pc.z *= P4.z;
        hc.w = fmaf(P4.w, hc.w, H4.w); pc.w *= P4.w;
    }
    *(float4*)(Pg + (size_t)g * H + j4) = pc;
    *(float4*)(Hg + (size_t)g * H + j4) = hc;
}

// ---- scan pass 2b: sequential combine over 32 groups (1 block, 512 threads) ----
__global__ void scan2b_kernel(const float* __restrict__ Pg, const float* __restrict__ Hg,
                              float* __restrict__ Cg){
    const int j = threadIdx.x;
    float carry = 0.0f;
    for (int g0 = 0; g0 < NGRP; g0 += 8){
        float p[8], h[8];
        #pragma unroll
        for (int i = 0; i < 8; i++){
            p[i] = Pg[(size_t)(g0 + i) * H + j];
            h[i] = Hg[(size_t)(g0 + i) * H + j];
        }
        #pragma unroll
        for (int i = 0; i < 8; i++){
            Cg[(size_t)(g0 + i) * H + j] = carry;
            carry = fmaf(p[i], carry, h[i]);
        }
    }
}

// ---- scan pass 3 (layer 0): re-apply with h0 = Sloc + Pp*Cg, y -> bf16 [T][H] ----
__global__ void scan3_bf16_kernel(const float* __restrict__ aT, const unsigned short* __restrict__ bxT,
                                  const unsigned short* __restrict__ CT,
                                  const float* __restrict__ Sloc, const float* __restrict__ Pp,
                                  const float* __restrict__ Cg,
                                  unsigned short* __restrict__ yb){
    int idx = blockIdx.x * 256 + threadIdx.x;
    int j4 = (idx & 127) * 4;
    int c  = idx >> 7;
    int nb = j4 >> 5, jj = j4 & 31;
    size_t so = (size_t)c * H + j4;
    size_t go = (size_t)(c >> 4) * H + j4;
    float4 sl = *(const float4*)(Sloc + so);
    float4 pp = *(const float4*)(Pp + so);
    float4 cg = *(const float4*)(Cg + go);
    float4 h;
    h.x = fmaf(pp.x, cg.x, sl.x);
    h.y = fmaf(pp.y, cg.y, sl.y);
    h.z = fmaf(pp.z, cg.z, sl.z);
    h.w = fmaf(pp.w, cg.w, sl.w);
    size_t off = (size_t)nb * SLAB + (size_t)c * CHUNK * 32 + jj;
    size_t yo  = (size_t)c * CHUNK * H + j4;
    #pragma unroll 4
    for (int i = 0; i < CHUNK; i++){
        float4 av  = *(const float4*)(aT + off);
        ushort4 bv = *(const ushort4*)(bxT + off);
        ushort4 cv = *(const ushort4*)(CT + off);
        h.x = fmaf(av.x, h.x, bf2f(bv.x));
        h.y = fmaf(av.y, h.y, bf2f(bv.y));
        h.z = fmaf(av.z, h.z, bf2f(bv.z));
        h.w = fmaf(av.w, h.w, bf2f(bv.w));
        ushort4 o;
        o.x = f2bf(bf2f(cv.x) * h.x);
        o.y = f2bf(bf2f(cv.y) * h.y);
        o.z = f2bf(bf2f(cv.z) * h.z);
        o.w = f2bf(bf2f(cv.w) * h.w);
        *(ushort4*)(yb + yo) = o;
        off += 32; yo += H;
    }
}

// ---- scan pass 3 (layer 1): y2 fp32 [T][H] for final GEMM ----
__global__ void scan3_f32_kernel(const float* __restrict__ aT, const unsigned short* __restrict__ bxT,
                                 const unsigned short* __restrict__ CT,
                                 const float* __restrict__ Sloc, const float* __restrict__ Pp,
                                 const float* __restrict__ Cg,
                                 float* __restrict__ y2){
    int idx = blockIdx.x * 256 + threadIdx.x;
    int j4 = (idx & 127) * 4;
    int c  = idx >> 7;
    int nb = j4 >> 5, jj = j4 & 31;
    size_t so = (size_t)c * H + j4;
    size_t go = (size_t)(c >> 4) * H + j4;
    float4 sl = *(const float4*)(Sloc + so);
    float4 pp = *(const float4*)(Pp + so);
    float4 cg = *(const float4*)(Cg + go);
    float4 h;
    h.x = fmaf(pp.x, cg.x, sl.x);
    h.y = fmaf(pp.y, cg.y, sl.y);
    h.z = fmaf(pp.z, cg.z, sl.z);
    h.w = fmaf(pp.w, cg.w, sl.w);
    size_t off = (size_t)nb * SLAB + (size_t)c * CHUNK * 32 + jj;
    size_t yo  = (size_t)c * CHUNK * H + j4;
    #pragma unroll 4
    for (int i = 0; i < CHUNK; i++){
        float4 av  = *(const float4*)(aT + off);
        ushort4 bv = *(const ushort4*)(bxT + off);
        ushort4 cv = *(const ushort4*)(CT + off);
        h.x = fmaf(av.x, h.x, bf2f(bv.x));
        h.y = fmaf(av.y, h.y, bf2f(bv.y));
        h.z = fmaf(av.z, h.z, bf2f(bv.z));
        h.w = fmaf(av.w, h.w, bf2f(bv.w));
        float4 o;
        o.x = bf2f(cv.x) * h.x;
        o.y = bf2f(cv.y) * h.y;
        o.z = bf2f(cv.z) * h.z;
        o.w = bf2f(cv.w) * h.w;
        *(float4*)(y2 + yo) = o;
        off += 32; yo += H;
    }
}

// ---- final: out[t][0:4] = y2[t]@W_out + b_out + x[t]@W_skip  (fp32, wave per row) ----
__global__ __launch_bounds__(256) void final_kernel(const float* __restrict__ y2,
                                                    const float* __restrict__ x,
                                                    const float* __restrict__ Wout,
                                                    const float* __restrict__ bout,
                                                    const float* __restrict__ Wskip,
                                                    float* __restrict__ out){
    int wave = threadIdx.x >> 6;
    int lane = threadIdx.x & 63;
    int t = blockIdx.x * 4 + wave;
    float s0 = 0.f, s1 = 0.f, s2 = 0.f, s3 = 0.f;
    const float4* W4 = (const float4*)Wout;
    #pragma unroll
    for (int k = lane; k < H; k += 64){
        float yv = y2[(size_t)t * H + k];
        float4 w = W4[k];
        s0 = fmaf(yv, w.x, s0); s1 = fmaf(yv, w.y, s1);
        s2 = fmaf(yv, w.z, s2); s3 = fmaf(yv, w.w, s3);
    }
    const float4* S4 = (const float4*)Wskip;
    #pragma unroll
    for (int k = lane; k < OBS; k += 64){
        float xv = x[(size_t)t * OBS + k];
        float4 w = S4[k];
        s0 = fmaf(xv, w.x, s0); s1 = fmaf(xv, w.y, s1);
        s2 = fmaf(xv, w.z, s2); s3 = fmaf(xv, w.w, s3);
    }
    #pragma unroll
    for (int off = 32; off > 0; off >>= 1){
        s0 += __shfl_down(s0, off);
        s1 += __shfl_down(s1, off);
        s2 += __shfl_down(s2, off);
        s3 += __shfl_down(s3, off);
    }
    if (lane == 0){
        out[(size_t)t * 4 + 0] = s0 + bout[0];
        out[(size_t)t * 4 + 1] = s1 + bout[1];
        out[(size_t)t * 4 + 2] = s2 + bout[2];
        out[(size_t)t * 4 + 3] = s3 + bout[3];
    }
}

extern "C" void kernel_launch(void* const* d_in, const int* in_sizes, int n_in,
                              void* d_out, int out_size, void* d_ws, size_t ws_size,
                              hipStream_t stream)
{
    const float* x     = (const float*)d_in[0];
    const float* W_in0 = (const float*)d_in[1];
    const float* W_B0  = (const float*)d_in[2];
    const float* W_C0  = (const float*)d_in[3];
    const float* W_d0  = (const float*)d_in[4];
    const float* A0    = (const float*)d_in[5];
    const float* W_in1 = (const float*)d_in[6];
    const float* W_B1  = (const float*)d_in[7];
    const float* W_C1  = (const float*)d_in[8];
    const float* W_d1  = (const float*)d_in[9];
    const float* A1    = (const float*)d_in[10];
    const float* Wout  = (const float*)d_in[11];
    const float* bout  = (const float*)d_in[12];
    const float* Wskip = (const float*)d_in[13];
    float* out = (float*)d_out;

    char* ws = (char*)d_ws;
    size_t off = 0;
    auto alloc = [&](size_t bytes) -> void* {
        void* p = ws + off;
        off += (bytes + 255) & ~(size_t)255;
        return p;
    };
    unsigned short* xb  = (unsigned short*)alloc((size_t)T_SIZE * OBS * 2);
    unsigned short* yb  = (unsigned short*)alloc((size_t)T_SIZE * H * 2);
    unsigned short* Wt0 = (unsigned short*)alloc((size_t)4 * H * OBS * 2);
    unsigned short* Wt1 = (unsigned short*)alloc((size_t)4 * H * H * 2);
    float*          aT  = (float*)alloc((size_t)T_SIZE * H * 4);
    unsigned short* bxT = (unsigned short*)alloc((size_t)T_SIZE * H * 2);
    unsigned short* CT  = (unsigned short*)alloc((size_t)T_SIZE * H * 2);
    float*          y2  = (float*)alloc((size_t)T_SIZE * H * 4);
    float* Pbuf = (float*)alloc((size_t)NC * H * 4);
    float* Hbuf = (float*)alloc((size_t)NC * H * 4);
    float* Sloc = (float*)alloc((size_t)NC * H * 4);
    float* Pp   = (float*)alloc((size_t)NC * H * 4);
    float* Pg   = (float*)alloc((size_t)NGRP * H * 4);
    float* Hg   = (float*)alloc((size_t)NGRP * H * 4);
    float* Cg   = (float*)alloc((size_t)NGRP * H * 4);
    (void)ws_size; (void)in_sizes; (void)n_in; (void)out_size;

    // ---- precision casts / weight transposes (interleaved layout) ----
    cast_x_kernel<<<(T_SIZE * OBS / 4 + 255) / 256, 256, 0, stream>>>(x, xb, T_SIZE * OBS / 4);
    tcast4_kernel<<<(4 * OBS * H + 255) / 256, 256, 0, stream>>>(W_in0, W_B0, W_C0, W_d0, Wt0, OBS, OBS * H);
    tcast4_kernel<<<(4 * H   * H + 255) / 256, 256, 0, stream>>>(W_in1, W_B1, W_C1, W_d1, Wt1, H,   H * H);

    dim3 ggrid(H / 32, T_SIZE / 128);   // nb fastest: 16 consecutive blocks share one A-panel
    const int sgrid = NC * 128 / 256;   // 256 blocks

    // ---- layer 0 ----
    gemm_layer_kernel<<<ggrid, 256, 0, stream>>>(xb, Wt0, A0, aT, bxT, CT, OBS);
    scan1_kernel<<<sgrid, 256, 0, stream>>>(aT, bxT, Pbuf, Hbuf);
    scan2a_kernel<<<NGRP, 128, 0, stream>>>(Pbuf, Hbuf, Sloc, Pp, Pg, Hg);
    scan2b_kernel<<<1, H, 0, stream>>>(Pg, Hg, Cg);
    scan3_bf16_kernel<<<sgrid, 256, 0, stream>>>(aT, bxT, CT, Sloc, Pp, Cg, yb);

    // ---- layer 1 ----
    gemm_layer_kernel<<<ggrid, 256, 0, stream>>>(yb, Wt1, A1, aT, bxT, CT, H);
    scan1_kernel<<<sgrid, 256, 0, stream>>>(aT, bxT, Pbuf, Hbuf);
    scan2a_kernel<<<NGRP, 128, 0, stream>>>(Pbuf, Hbuf, Sloc, Pp, Pg, Hg);
    scan2b_kernel<<<1, H, 0, stream>>>(Pg, Hg, Cg);
    scan3_f32_kernel<<<sgrid, 256, 0, stream>>>(aT, bxT, CT, Sloc, Pp, Cg, y2);

    // ---- output head ----
    final_kernel<<<T_SIZE / 4, 256, 0, stream>>>(y2, x, Wout, bout, Wskip, out);
}

// Round 5
// 375.941 us; speedup vs baseline: 1.8824x; 1.1146x over previous
//
#include <hip/hip_runtime.h>

typedef __attribute__((ext_vector_type(8))) short short8;
typedef __attribute__((ext_vector_type(4))) float floatx4;

#define T_SIZE 32768
#define OBS    256
#define H      512
#define NC     512     // scan chunks
#define CHUNK  64      // T_SIZE / NC
#define NGRP   32      // scan2 groups
#define GCH    16      // chunks per group
#define SLAB   ((size_t)T_SIZE * 32)   // one h-block slab in tiled layout

__device__ __forceinline__ unsigned short f2bf(float f){
    union { float f; unsigned u; } v; v.f = f;
    unsigned u = v.u;
    u += 0x7FFFu + ((u >> 16) & 1u);   // round-to-nearest-even
    return (unsigned short)(u >> 16);
}
__device__ __forceinline__ float bf2f(unsigned short u){
    union { unsigned u; float f; } v; v.u = ((unsigned)u) << 16; return v.f;
}

// async global->LDS, 16B per lane; lds base must be wave-uniform (HW adds lane*16)
#define GLOAD_LDS16(g, l) \
    __builtin_amdgcn_global_load_lds((const __attribute__((address_space(1))) unsigned*)(g), \
                                     (__attribute__((address_space(3))) unsigned*)(l), 16, 0, 0)

// ---- cast x [T,OBS] fp32 -> bf16, vectorized ----
__global__ void cast_x_kernel(const float* __restrict__ x, unsigned short* __restrict__ xb, int n4){
    int i = blockIdx.x * 256 + threadIdx.x;
    if (i < n4){
        float4 v = ((const float4*)x)[i];
        ushort4 o;
        o.x = f2bf(v.x); o.y = f2bf(v.y); o.z = f2bf(v.z); o.w = f2bf(v.w);
        ((ushort4*)xb)[i] = o;
    }
}

// ---- transpose+cast 4 weights W[K][512] fp32 -> interleaved [h/16][slot][16h][K] bf16 ----
__global__ void tcast4_kernel(const float* __restrict__ W0, const float* __restrict__ W1,
                              const float* __restrict__ W2, const float* __restrict__ W3,
                              unsigned short* __restrict__ dst, int K, int KH){
    int idx = blockIdx.x * 256 + threadIdx.x;
    if (idx >= 4 * KH) return;
    int s   = idx / KH;
    int rem = idx - s * KH;
    int k = rem >> 9;            // H == 512
    int h = rem & 511;
    const float* W = (s == 0) ? W0 : (s == 1) ? W1 : (s == 2) ? W2 : W3;
    int b = h >> 4, hh = h & 15;
    dst[(size_t)((b * 4 + s) * 16 + hh) * K + k] = f2bf(W[(size_t)k * H + h]);
}

// ---- fused 4-matrix GEMM + epilogue + chunk-scan aggregates (scan1 fused) ----
// xb: [T][K] bf16.  wt: [H/16][4 slots][16 h][K] bf16 (slot: 0=in,1=B,2=C,3=d).
// Outputs TILED: aT/bxT/CT are [H/32][T][32].  Also writes Pbuf/Hbuf [NC][H].
// Grid is flat-swizzled so all 16 nb-blocks of one mb land on one XCD (A-panel L2 reuse).
__global__ __launch_bounds__(256) void gemm_layer_kernel(
    const unsigned short* __restrict__ xb,
    const unsigned short* __restrict__ wt,
    const float* __restrict__ A_log,
    float* __restrict__ aT, unsigned short* __restrict__ bxT, unsigned short* __restrict__ CT,
    float* __restrict__ Pbuf, float* __restrict__ Hbuf,
    int K)
{
    __shared__ unsigned short SM[2 * 128 * 32];    // 16 KB: A panel | B panel; reused by epilogue
    unsigned short* Asm = SM;
    unsigned short* Bsm = SM + 128 * 32;

    const int tid  = threadIdx.x;
    const int wave = tid >> 6;
    const int lane = tid & 63;
    const int ml   = lane & 15;
    const int quad = lane >> 4;
    const int wm   = wave & 1;
    const int wn   = wave >> 1;

    // XCD-aware swizzle: flat dispatch order -> (nb, mb) with one XCD per A-panel group
    const int flat = blockIdx.y * 16 + blockIdx.x;
    const int xcd  = flat & 7;
    const int j    = flat >> 3;
    const int nb   = j & 15;                 // 0..15 : h block of 32
    const int mb   = (j >> 4) * 8 + xcd;     // 0..255 : t tile of 128
    const int m0   = mb * 128;

    const unsigned short* gA = xb + (size_t)m0 * K;
    const unsigned short* gB = wt + (size_t)nb * 128 * K;

    const int srow = tid >> 2;
    const int sel  = (((tid & 3) ^ ((tid >> 3) & 3))) * 8;
    const int swz  = (ml >> 1) & 3;         // read-side XOR swizzle

    floatx4 acc[4][4];
    #pragma unroll
    for (int i = 0; i < 4; i++)
        #pragma unroll
        for (int jj = 0; jj < 4; jj++)
            acc[i][jj] = (floatx4)(0.0f);

    for (int k0 = 0; k0 < K; k0 += 32){
        GLOAD_LDS16(gA + (size_t)(srow      ) * K + k0 + sel, Asm + (size_t)(wave * 64 + 0  ) * 8);
        GLOAD_LDS16(gA + (size_t)(srow + 64 ) * K + k0 + sel, Asm + (size_t)(wave * 64 + 256) * 8);
        GLOAD_LDS16(gB + (size_t)(srow      ) * K + k0 + sel, Bsm + (size_t)(wave * 64 + 0  ) * 8);
        GLOAD_LDS16(gB + (size_t)(srow + 64 ) * K + k0 + sel, Bsm + (size_t)(wave * 64 + 256) * 8);
        __syncthreads();

        short8 av[4], bv[4];
        #pragma unroll
        for (int i = 0; i < 4; i++)
            av[i] = *(const short8*)(Asm + (size_t)(wm * 64 + i * 16 + ml) * 32 + (quad ^ swz) * 8);
        #pragma unroll
        for (int jj = 0; jj < 4; jj++)
            bv[jj] = *(const short8*)(Bsm + (size_t)(wn * 64 + jj * 16 + ml) * 32 + (quad ^ swz) * 8);

        #pragma unroll
        for (int i = 0; i < 4; i++)
            #pragma unroll
            for (int jj = 0; jj < 4; jj++)
                acc[i][jj] = __builtin_amdgcn_mfma_f32_16x16x32_bf16(av[i], bv[jj], acc[i][jj], 0, 0, 0);
        __syncthreads();
    }

    // ---- epilogue: slots 0=x_state, 1=B, 2=C, 3=d ----
    const int col = wn * 16 + ml;            // 0..31 h within block
    const int h   = nb * 32 + col;
    const float Aneg = -expf(A_log[h]);

    float segp[4], segh[4];                   // per-i 4-step scan segment aggregates (chunk = wm)

    // round 1: a_bar fp32 -> LDS; also fold segment aggregates from unrounded regs
    float* smf = (float*)SM;
    #pragma unroll
    for (int i = 0; i < 4; i++){
        float p = 1.0f, hh = 0.0f;
        #pragma unroll
        for (int r = 0; r < 4; r++){
            int trow = wm * 64 + i * 16 + quad * 4 + r;   // C/D: row = quad*4 + reg
            float dv = acc[i][3][r];
            float delta = 1.0f / (1.0f + expf(-dv));
            float a  = expf(delta * Aneg);
            float bx = acc[i][1][r] * acc[i][0][r];
            smf[trow * 32 + col] = a;
            hh = fmaf(a, hh, bx);
            p *= a;
        }
        segp[i] = p; segh[i] = hh;
    }
    __syncthreads();
    {
        const float4* src = (const float4*)smf;
        float4* dst = (float4*)(aT + (size_t)nb * SLAB + (size_t)m0 * 32);
        #pragma unroll
        for (int v = 0; v < 4; v++) dst[tid + v * 256] = src[tid + v * 256];
    }
    __syncthreads();

    // round 2: bx (bf16, 8 KB) + C (bf16, 8 KB)
    #pragma unroll
    for (int i = 0; i < 4; i++){
        #pragma unroll
        for (int r = 0; r < 4; r++){
            int trow = wm * 64 + i * 16 + quad * 4 + r;
            SM[trow * 32 + col]        = f2bf(acc[i][1][r] * acc[i][0][r]);   // B * x_state
            SM[4096 + trow * 32 + col] = f2bf(acc[i][2][r]);                  // C
        }
    }
    __syncthreads();
    {
        const short8* s8 = (const short8*)SM;
        short8* db = (short8*)(bxT + (size_t)nb * SLAB + (size_t)m0 * 32);
        short8* dc = (short8*)(CT  + (size_t)nb * SLAB + (size_t)m0 * 32);
        db[tid] = s8[tid];       db[tid + 256] = s8[tid + 256];
        dc[tid] = s8[512 + tid]; dc[tid + 256] = s8[768 + tid];
    }
    __syncthreads();

    // round 3: compose the 16 ordered segments per (chunk, col) -> chunk aggregates (scan1)
    float2* segbuf = (float2*)SM;            // [seg 16][col 32][chunk 2] = 8 KB
    #pragma unroll
    for (int i = 0; i < 4; i++)
        segbuf[(i * 4 + quad) * 64 + col * 2 + wm] = make_float2(segp[i], segh[i]);
    __syncthreads();
    if (tid < 64){
        int ccol = tid >> 1, ch = tid & 1;
        float P = 1.0f, Hc = 0.0f;
        #pragma unroll
        for (int s = 0; s < 16; s++){
            float2 ph = segbuf[s * 64 + ccol * 2 + ch];
            Hc = fmaf(ph.x, Hc, ph.y);
            P *= ph.x;
        }
        int c = mb * 2 + ch;
        Pbuf[(size_t)c * H + nb * 32 + ccol] = P;
        Hbuf[(size_t)c * H + nb * 32 + ccol] = Hc;
    }
}

// ---- scan pass 2a: 32 groups x 16 chunks, local exclusive prefix + group aggregate ----
__global__ void scan2a_kernel(const float* __restrict__ P, const float* __restrict__ Hc,
                              float* __restrict__ Sloc, float* __restrict__ Pp,
                              float* __restrict__ Pg, float* __restrict__ Hg){
    const int g  = blockIdx.x;          // 0..31
    const int j4 = threadIdx.x * 4;     // 128 threads
    float4 pc = {1.f,1.f,1.f,1.f}, hc = {0.f,0.f,0.f,0.f};
    #pragma unroll
    for (int i = 0; i < GCH; i++){
        size_t o = (size_t)(g * GCH + i) * H + j4;
        float4 P4 = *(const float4*)(P + o);
        float4 H4 = *(const float4*)(Hc + o);
        *(float4*)(Sloc + o) = hc;
        *(float4*)(Pp   + o) = pc;
        hc.x = fmaf(P4.x, hc.x, H4.x); pc.x *= P4.x;
        hc.y = fmaf(P4.y, hc.y, H4.y); pc.y *= P4.y;
        hc.z = fmaf(P4.z, hc.z, H4.z); pc.z *= P4.z;
        hc.w = fmaf(P4.w, hc.w, H4.w); pc.w *= P4.w;
    }
    *(float4*)(Pg + (size_t)g * H + j4) = pc;
    *(float4*)(Hg + (size_t)g * H + j4) = hc;
}

// ---- scan pass 2b: sequential combine over 32 groups (1 block, 512 threads) ----
__global__ void scan2b_kernel(const float* __restrict__ Pg, const float* __restrict__ Hg,
                              float* __restrict__ Cg){
    const int j = threadIdx.x;
    float carry = 0.0f;
    for (int g0 = 0; g0 < NGRP; g0 += 8){
        float p[8], h[8];
        #pragma unroll
        for (int i = 0; i < 8; i++){
            p[i] = Pg[(size_t)(g0 + i) * H + j];
            h[i] = Hg[(size_t)(g0 + i) * H + j];
        }
        #pragma unroll
        for (int i = 0; i < 8; i++){
            Cg[(size_t)(g0 + i) * H + j] = carry;
            carry = fmaf(p[i], carry, h[i]);
        }
    }
}

// ---- scan pass 3: re-apply with h0 = Sloc + Pp*Cg, write y = C*h as bf16 [T][H] ----
__global__ void scan3_bf16_kernel(const float* __restrict__ aT, const unsigned short* __restrict__ bxT,
                                  const unsigned short* __restrict__ CT,
                                  const float* __restrict__ Sloc, const float* __restrict__ Pp,
                                  const float* __restrict__ Cg,
                                  unsigned short* __restrict__ yb){
    int idx = blockIdx.x * 256 + threadIdx.x;
    int j4 = (idx & 127) * 4;
    int c  = idx >> 7;
    int nb = j4 >> 5, jj = j4 & 31;
    size_t so = (size_t)c * H + j4;
    size_t go = (size_t)(c >> 4) * H + j4;
    float4 sl = *(const float4*)(Sloc + so);
    float4 pp = *(const float4*)(Pp + so);
    float4 cg = *(const float4*)(Cg + go);
    float4 h;
    h.x = fmaf(pp.x, cg.x, sl.x);
    h.y = fmaf(pp.y, cg.y, sl.y);
    h.z = fmaf(pp.z, cg.z, sl.z);
    h.w = fmaf(pp.w, cg.w, sl.w);
    size_t off = (size_t)nb * SLAB + (size_t)c * CHUNK * 32 + jj;
    size_t yo  = (size_t)c * CHUNK * H + j4;
    #pragma unroll 4
    for (int i = 0; i < CHUNK; i++){
        float4 av  = *(const float4*)(aT + off);
        ushort4 bv = *(const ushort4*)(bxT + off);
        ushort4 cv = *(const ushort4*)(CT + off);
        h.x = fmaf(av.x, h.x, bf2f(bv.x));
        h.y = fmaf(av.y, h.y, bf2f(bv.y));
        h.z = fmaf(av.z, h.z, bf2f(bv.z));
        h.w = fmaf(av.w, h.w, bf2f(bv.w));
        ushort4 o;
        o.x = f2bf(bf2f(cv.x) * h.x);
        o.y = f2bf(bf2f(cv.y) * h.y);
        o.z = f2bf(bf2f(cv.z) * h.z);
        o.w = f2bf(bf2f(cv.w) * h.w);
        *(ushort4*)(yb + yo) = o;
        off += 32; yo += H;
    }
}

// ---- final: out[t][0:4] = y2[t]@W_out + b_out + x[t]@W_skip  (y2 bf16, wave per row) ----
__global__ __launch_bounds__(256) void final_kernel(const unsigned short* __restrict__ y2,
                                                    const float* __restrict__ x,
                                                    const float* __restrict__ Wout,
                                                    const float* __restrict__ bout,
                                                    const float* __restrict__ Wskip,
                                                    float* __restrict__ out){
    int wave = threadIdx.x >> 6;
    int lane = threadIdx.x & 63;
    int t = blockIdx.x * 4 + wave;
    float s0 = 0.f, s1 = 0.f, s2 = 0.f, s3 = 0.f;
    const float4* W4 = (const float4*)Wout;
    #pragma unroll
    for (int k = lane; k < H; k += 64){
        float yv = bf2f(y2[(size_t)t * H + k]);
        float4 w = W4[k];
        s0 = fmaf(yv, w.x, s0); s1 = fmaf(yv, w.y, s1);
        s2 = fmaf(yv, w.z, s2); s3 = fmaf(yv, w.w, s3);
    }
    const float4* S4 = (const float4*)Wskip;
    #pragma unroll
    for (int k = lane; k < OBS; k += 64){
        float xv = x[(size_t)t * OBS + k];
        float4 w = S4[k];
        s0 = fmaf(xv, w.x, s0); s1 = fmaf(xv, w.y, s1);
        s2 = fmaf(xv, w.z, s2); s3 = fmaf(xv, w.w, s3);
    }
    #pragma unroll
    for (int off = 32; off > 0; off >>= 1){
        s0 += __shfl_down(s0, off);
        s1 += __shfl_down(s1, off);
        s2 += __shfl_down(s2, off);
        s3 += __shfl_down(s3, off);
    }
    if (lane == 0){
        out[(size_t)t * 4 + 0] = s0 + bout[0];
        out[(size_t)t * 4 + 1] = s1 + bout[1];
        out[(size_t)t * 4 + 2] = s2 + bout[2];
        out[(size_t)t * 4 + 3] = s3 + bout[3];
    }
}

extern "C" void kernel_launch(void* const* d_in, const int* in_sizes, int n_in,
                              void* d_out, int out_size, void* d_ws, size_t ws_size,
                              hipStream_t stream)
{
    const float* x     = (const float*)d_in[0];
    const float* W_in0 = (const float*)d_in[1];
    const float* W_B0  = (const float*)d_in[2];
    const float* W_C0  = (const float*)d_in[3];
    const float* W_d0  = (const float*)d_in[4];
    const float* A0    = (const float*)d_in[5];
    const float* W_in1 = (const float*)d_in[6];
    const float* W_B1  = (const float*)d_in[7];
    const float* W_C1  = (const float*)d_in[8];
    const float* W_d1  = (const float*)d_in[9];
    const float* A1    = (const float*)d_in[10];
    const float* Wout  = (const float*)d_in[11];
    const float* bout  = (const float*)d_in[12];
    const float* Wskip = (const float*)d_in[13];
    float* out = (float*)d_out;

    char* ws = (char*)d_ws;
    size_t off = 0;
    auto alloc = [&](size_t bytes) -> void* {
        void* p = ws + off;
        off += (bytes + 255) & ~(size_t)255;
        return p;
    };
    unsigned short* xb  = (unsigned short*)alloc((size_t)T_SIZE * OBS * 2);
    unsigned short* yb  = (unsigned short*)alloc((size_t)T_SIZE * H * 2);  // layer0 y; reused for layer1 y
    unsigned short* Wt0 = (unsigned short*)alloc((size_t)4 * H * OBS * 2);
    unsigned short* Wt1 = (unsigned short*)alloc((size_t)4 * H * H * 2);
    float*          aT  = (float*)alloc((size_t)T_SIZE * H * 4);
    unsigned short* bxT = (unsigned short*)alloc((size_t)T_SIZE * H * 2);
    unsigned short* CT  = (unsigned short*)alloc((size_t)T_SIZE * H * 2);
    float* Pbuf = (float*)alloc((size_t)NC * H * 4);
    float* Hbuf = (float*)alloc((size_t)NC * H * 4);
    float* Sloc = (float*)alloc((size_t)NC * H * 4);
    float* Pp   = (float*)alloc((size_t)NC * H * 4);
    float* Pg   = (float*)alloc((size_t)NGRP * H * 4);
    float* Hg   = (float*)alloc((size_t)NGRP * H * 4);
    float* Cg   = (float*)alloc((size_t)NGRP * H * 4);
    (void)ws_size; (void)in_sizes; (void)n_in; (void)out_size;

    // ---- precision casts / weight transposes (interleaved layout) ----
    cast_x_kernel<<<(T_SIZE * OBS / 4 + 255) / 256, 256, 0, stream>>>(x, xb, T_SIZE * OBS / 4);
    tcast4_kernel<<<(4 * OBS * H + 255) / 256, 256, 0, stream>>>(W_in0, W_B0, W_C0, W_d0, Wt0, OBS, OBS * H);
    tcast4_kernel<<<(4 * H   * H + 255) / 256, 256, 0, stream>>>(W_in1, W_B1, W_C1, W_d1, Wt1, H,   H * H);

    dim3 ggrid(16, 256);                 // flat-swizzled inside the kernel
    const int sgrid = NC * 128 / 256;    // 256 blocks

    // ---- layer 0 ----
    gemm_layer_kernel<<<ggrid, 256, 0, stream>>>(xb, Wt0, A0, aT, bxT, CT, Pbuf, Hbuf, OBS);
    scan2a_kernel<<<NGRP, 128, 0, stream>>>(Pbuf, Hbuf, Sloc, Pp, Pg, Hg);
    scan2b_kernel<<<1, H, 0, stream>>>(Pg, Hg, Cg);
    scan3_bf16_kernel<<<sgrid, 256, 0, stream>>>(aT, bxT, CT, Sloc, Pp, Cg, yb);

    // ---- layer 1 ----
    gemm_layer_kernel<<<ggrid, 256, 0, stream>>>(yb, Wt1, A1, aT, bxT, CT, Pbuf, Hbuf, H);
    scan2a_kernel<<<NGRP, 128, 0, stream>>>(Pbuf, Hbuf, Sloc, Pp, Pg, Hg);
    scan2b_kernel<<<1, H, 0, stream>>>(Pg, Hg, Cg);
    scan3_bf16_kernel<<<sgrid, 256, 0, stream>>>(aT, bxT, CT, Sloc, Pp, Cg, yb /*reuse: layer1 y*/);

    // ---- output head ----
    final_kernel<<<T_SIZE / 4, 256, 0, stream>>>(yb, x, Wout, bout, Wskip, out);
}

// Round 6
// 366.576 us; speedup vs baseline: 1.9305x; 1.0255x over previous
//
#include <hip/hip_runtime.h>

typedef __attribute__((ext_vector_type(8))) short short8;
typedef __attribute__((ext_vector_type(4))) float floatx4;

#define T_SIZE 32768
#define OBS    256
#define H      512
#define NC     512     // scan chunks
#define CHUNK  64      // T_SIZE / NC
#define NGRP   32      // scan2 groups
#define GCH    16      // chunks per group
#define SLAB   ((size_t)T_SIZE * 32)   // one h-block slab in tiled layout

__device__ __forceinline__ unsigned short f2bf(float f){
    union { float f; unsigned u; } v; v.f = f;
    unsigned u = v.u;
    u += 0x7FFFu + ((u >> 16) & 1u);   // round-to-nearest-even
    return (unsigned short)(u >> 16);
}
__device__ __forceinline__ float bf2f(unsigned short u){
    union { unsigned u; float f; } v; v.u = ((unsigned)u) << 16; return v.f;
}

// async global->LDS, 16B per lane; lds base must be wave-uniform (HW adds lane*16)
#define GLOAD_LDS16(g, l) \
    __builtin_amdgcn_global_load_lds((const __attribute__((address_space(1))) unsigned*)(g), \
                                     (__attribute__((address_space(3))) unsigned*)(l), 16, 0, 0)

// ---- cast x [T,OBS] fp32 -> bf16, vectorized ----
__global__ void cast_x_kernel(const float* __restrict__ x, unsigned short* __restrict__ xb, int n4){
    int i = blockIdx.x * 256 + threadIdx.x;
    if (i < n4){
        float4 v = ((const float4*)x)[i];
        ushort4 o;
        o.x = f2bf(v.x); o.y = f2bf(v.y); o.z = f2bf(v.z); o.w = f2bf(v.w);
        ((ushort4*)xb)[i] = o;
    }
}

// ---- transpose+cast 4 weights W[K][512] fp32 -> interleaved [h/16][slot][16h][K] bf16 ----
__global__ void tcast4_kernel(const float* __restrict__ W0, const float* __restrict__ W1,
                              const float* __restrict__ W2, const float* __restrict__ W3,
                              unsigned short* __restrict__ dst, int K, int KH){
    int idx = blockIdx.x * 256 + threadIdx.x;
    if (idx >= 4 * KH) return;
    int s   = idx / KH;
    int rem = idx - s * KH;
    int k = rem >> 9;            // H == 512
    int h = rem & 511;
    const float* W = (s == 0) ? W0 : (s == 1) ? W1 : (s == 2) ? W2 : W3;
    int b = h >> 4, hh = h & 15;
    dst[(size_t)((b * 4 + s) * 16 + hh) * K + k] = f2bf(W[(size_t)k * H + h]);
}

// ---- fused 4-matrix GEMM (double-buffered LDS, 1 barrier/iter) + epilogue + scan1 fused ----
// xb: [T][K] bf16.  wt: [H/16][4 slots][16 h][K] bf16 (slot: 0=in,1=B,2=C,3=d).
// Outputs TILED: aT/bxT/CT are [H/32][T][32].  Also writes Pbuf/Hbuf [NC][H].
__global__ __launch_bounds__(256) void gemm_layer_kernel(
    const unsigned short* __restrict__ xb,
    const unsigned short* __restrict__ wt,
    const float* __restrict__ A_log,
    float* __restrict__ aT, unsigned short* __restrict__ bxT, unsigned short* __restrict__ CT,
    float* __restrict__ Pbuf, float* __restrict__ Hbuf,
    int K)
{
    // two 16 KB buffers: [buf][A(4096 shorts) | B(4096 shorts)]
    __shared__ unsigned short SM[2][8192];

    const int tid  = threadIdx.x;
    const int wave = tid >> 6;
    const int lane = tid & 63;
    const int ml   = lane & 15;
    const int quad = lane >> 4;
    const int wm   = wave & 1;
    const int wn   = wave >> 1;

    // XCD-aware swizzle: all 16 nb-blocks of one mb land on one XCD (A-panel L2 reuse)
    const int flat = blockIdx.y * 16 + blockIdx.x;
    const int xcd  = flat & 7;
    const int j    = flat >> 3;
    const int nb   = j & 15;                 // 0..15 : h block of 32
    const int mb   = (j >> 4) * 8 + xcd;     // 0..255 : t tile of 128
    const int m0   = mb * 128;

    const int srow = tid >> 2;
    const int sel  = (((tid & 3) ^ ((tid >> 3) & 3))) * 8;   // staging XOR swizzle
    const int swz  = (ml >> 1) & 3;                          // read-side XOR swizzle

    // hoisted staging pointers (bump by 32 elements per K-step)
    const unsigned short* pa0 = xb + (size_t)(m0 + srow) * K + sel;
    const unsigned short* pa1 = pa0 + (size_t)64 * K;
    const unsigned short* pb0 = wt + (size_t)(nb * 128 + srow) * K + sel;
    const unsigned short* pb1 = pb0 + (size_t)64 * K;

    const int ldsA0 = (wave * 64 + 0  ) * 8;
    const int ldsA1 = (wave * 64 + 256) * 8;

    floatx4 acc[4][4];
    #pragma unroll
    for (int i = 0; i < 4; i++)
        #pragma unroll
        for (int jj = 0; jj < 4; jj++)
            acc[i][jj] = (floatx4)(0.0f);

    // prologue: stage K-step 0 into buf 0
    GLOAD_LDS16(pa0, &SM[0][ldsA0]);
    GLOAD_LDS16(pa1, &SM[0][ldsA1]);
    GLOAD_LDS16(pb0, &SM[0][4096 + ldsA0]);
    GLOAD_LDS16(pb1, &SM[0][4096 + ldsA1]);

    const int nk = K >> 5;
    for (int kk = 0; kk < nk; ++kk){
        __syncthreads();   // drains DMA issued one full compute phase ago (cheap);
                           // rendezvous makes single-barrier dbuf safe
        const int cur = kk & 1;
        if (kk + 1 < nk){
            const int nxt = cur ^ 1;
            const int ko  = (kk + 1) * 32;
            GLOAD_LDS16(pa0 + ko, &SM[nxt][ldsA0]);
            GLOAD_LDS16(pa1 + ko, &SM[nxt][ldsA1]);
            GLOAD_LDS16(pb0 + ko, &SM[nxt][4096 + ldsA0]);
            GLOAD_LDS16(pb1 + ko, &SM[nxt][4096 + ldsA1]);
        }

        const unsigned short* As = &SM[cur][0];
        const unsigned short* Bs = &SM[cur][4096];
        short8 av[4], bv[4];
        #pragma unroll
        for (int i = 0; i < 4; i++)
            av[i] = *(const short8*)(As + (size_t)(wm * 64 + i * 16 + ml) * 32 + (quad ^ swz) * 8);
        #pragma unroll
        for (int jj = 0; jj < 4; jj++)
            bv[jj] = *(const short8*)(Bs + (size_t)(wn * 64 + jj * 16 + ml) * 32 + (quad ^ swz) * 8);

        #pragma unroll
        for (int i = 0; i < 4; i++)
            #pragma unroll
            for (int jj = 0; jj < 4; jj++)
                acc[i][jj] = __builtin_amdgcn_mfma_f32_16x16x32_bf16(av[i], bv[jj], acc[i][jj], 0, 0, 0);
    }
    __syncthreads();   // all LDS reads done before epilogue reuses SM

    // ---- epilogue: slots 0=x_state, 1=B, 2=C, 3=d ----
    unsigned short* SMe = &SM[0][0];
    const int col = wn * 16 + ml;            // 0..31 h within block
    const int h   = nb * 32 + col;
    const float Aneg = -expf(A_log[h]);

    float segp[4], segh[4];                  // per-i 4-step scan segment aggregates (chunk = wm)

    // round 1: a_bar fp32 -> LDS; also fold segment aggregates from unrounded regs
    float* smf = (float*)SMe;
    #pragma unroll
    for (int i = 0; i < 4; i++){
        float p = 1.0f, hh = 0.0f;
        #pragma unroll
        for (int r = 0; r < 4; r++){
            int trow = wm * 64 + i * 16 + quad * 4 + r;   // C/D: row = quad*4 + reg
            float dv = acc[i][3][r];
            float delta = 1.0f / (1.0f + expf(-dv));
            float a  = expf(delta * Aneg);
            float bx = acc[i][1][r] * acc[i][0][r];
            smf[trow * 32 + col] = a;
            hh = fmaf(a, hh, bx);
            p *= a;
        }
        segp[i] = p; segh[i] = hh;
    }
    __syncthreads();
    {
        const float4* src = (const float4*)smf;
        float4* dst = (float4*)(aT + (size_t)nb * SLAB + (size_t)m0 * 32);
        #pragma unroll
        for (int v = 0; v < 4; v++) dst[tid + v * 256] = src[tid + v * 256];
    }
    __syncthreads();

    // round 2: bx (bf16, 8 KB) + C (bf16, 8 KB)
    #pragma unroll
    for (int i = 0; i < 4; i++){
        #pragma unroll
        for (int r = 0; r < 4; r++){
            int trow = wm * 64 + i * 16 + quad * 4 + r;
            SMe[trow * 32 + col]        = f2bf(acc[i][1][r] * acc[i][0][r]);   // B * x_state
            SMe[4096 + trow * 32 + col] = f2bf(acc[i][2][r]);                  // C
        }
    }
    __syncthreads();
    {
        const short8* s8 = (const short8*)SMe;
        short8* db = (short8*)(bxT + (size_t)nb * SLAB + (size_t)m0 * 32);
        short8* dc = (short8*)(CT  + (size_t)nb * SLAB + (size_t)m0 * 32);
        db[tid] = s8[tid];       db[tid + 256] = s8[tid + 256];
        dc[tid] = s8[512 + tid]; dc[tid + 256] = s8[768 + tid];
    }
    __syncthreads();

    // round 3: compose the 16 ordered segments per (chunk, col) -> chunk aggregates (scan1)
    float2* segbuf = (float2*)SMe;           // [seg 16][col 32][chunk 2] = 8 KB
    #pragma unroll
    for (int i = 0; i < 4; i++)
        segbuf[(i * 4 + quad) * 64 + col * 2 + wm] = make_float2(segp[i], segh[i]);
    __syncthreads();
    if (tid < 64){
        int ccol = tid >> 1, ch = tid & 1;
        float P = 1.0f, Hc = 0.0f;
        #pragma unroll
        for (int s = 0; s < 16; s++){
            float2 ph = segbuf[s * 64 + ccol * 2 + ch];
            Hc = fmaf(ph.x, Hc, ph.y);
            P *= ph.x;
        }
        int c = mb * 2 + ch;
        Pbuf[(size_t)c * H + nb * 32 + ccol] = P;
        Hbuf[(size_t)c * H + nb * 32 + ccol] = Hc;
    }
}

// ---- scan pass 2a: 32 groups x 16 chunks, local exclusive prefix + group aggregate ----
__global__ void scan2a_kernel(const float* __restrict__ P, const float* __restrict__ Hc,
                              float* __restrict__ Sloc, float* __restrict__ Pp,
                              float* __restrict__ Pg, float* __restrict__ Hg){
    const int g  = blockIdx.x;          // 0..31
    const int j4 = threadIdx.x * 4;     // 128 threads
    float4 pc = {1.f,1.f,1.f,1.f}, hc = {0.f,0.f,0.f,0.f};
    #pragma unroll
    for (int i = 0; i < GCH; i++){
        size_t o = (size_t)(g * GCH + i) * H + j4;
        float4 P4 = *(const float4*)(P + o);
        float4 H4 = *(const float4*)(Hc + o);
        *(float4*)(Sloc + o) = hc;
        *(float4*)(Pp   + o) = pc;
        hc.x = fmaf(P4.x, hc.x, H4.x); pc.x *= P4.x;
        hc.y = fmaf(P4.y, hc.y, H4.y); pc.y *= P4.y;
        hc.z = fmaf(P4.z, hc.z, H4.z); pc.z *= P4.z;
        hc.w = fmaf(P4.w, hc.w, H4.w); pc.w *= P4.w;
    }
    *(float4*)(Pg + (size_t)g * H + j4) = pc;
    *(float4*)(Hg + (size_t)g * H + j4) = hc;
}

// ---- scan pass 2b: sequential combine over 32 groups (1 block, 512 threads) ----
__global__ void scan2b_kernel(const float* __restrict__ Pg, const float* __restrict__ Hg,
                              float* __restrict__ Cg){
    const int j = threadIdx.x;
    float carry = 0.0f;
    for (int g0 = 0; g0 < NGRP; g0 += 8){
        float p[8], h[8];
        #pragma unroll
        for (int i = 0; i < 8; i++){
            p[i] = Pg[(size_t)(g0 + i) * H + j];
            h[i] = Hg[(size_t)(g0 + i) * H + j];
        }
        #pragma unroll
        for (int i = 0; i < 8; i++){
            Cg[(size_t)(g0 + i) * H + j] = carry;
            carry = fmaf(p[i], carry, h[i]);
        }
    }
}

// ---- scan pass 3: re-apply with h0 = Sloc + Pp*Cg, write y = C*h as bf16 [T][H] ----
__global__ void scan3_bf16_kernel(const float* __restrict__ aT, const unsigned short* __restrict__ bxT,
                                  const unsigned short* __restrict__ CT,
                                  const float* __restrict__ Sloc, const float* __restrict__ Pp,
                                  const float* __restrict__ Cg,
                                  unsigned short* __restrict__ yb){
    int idx = blockIdx.x * 256 + threadIdx.x;
    int j4 = (idx & 127) * 4;
    int c  = idx >> 7;
    int nb = j4 >> 5, jj = j4 & 31;
    size_t so = (size_t)c * H + j4;
    size_t go = (size_t)(c >> 4) * H + j4;
    float4 sl = *(const float4*)(Sloc + so);
    float4 pp = *(const float4*)(Pp + so);
    float4 cg = *(const float4*)(Cg + go);
    float4 h;
    h.x = fmaf(pp.x, cg.x, sl.x);
    h.y = fmaf(pp.y, cg.y, sl.y);
    h.z = fmaf(pp.z, cg.z, sl.z);
    h.w = fmaf(pp.w, cg.w, sl.w);
    size_t off = (size_t)nb * SLAB + (size_t)c * CHUNK * 32 + jj;
    size_t yo  = (size_t)c * CHUNK * H + j4;
    #pragma unroll 4
    for (int i = 0; i < CHUNK; i++){
        float4 av  = *(const float4*)(aT + off);
        ushort4 bv = *(const ushort4*)(bxT + off);
        ushort4 cv = *(const ushort4*)(CT + off);
        h.x = fmaf(av.x, h.x, bf2f(bv.x));
        h.y = fmaf(av.y, h.y, bf2f(bv.y));
        h.z = fmaf(av.z, h.z, bf2f(bv.z));
        h.w = fmaf(av.w, h.w, bf2f(bv.w));
        ushort4 o;
        o.x = f2bf(bf2f(cv.x) * h.x);
        o.y = f2bf(bf2f(cv.y) * h.y);
        o.z = f2bf(bf2f(cv.z) * h.z);
        o.w = f2bf(bf2f(cv.w) * h.w);
        *(ushort4*)(yb + yo) = o;
        off += 32; yo += H;
    }
}

// ---- final: out[t][0:4] = y2[t]@W_out + b_out + x[t]@W_skip  (y2 bf16, wave per row) ----
__global__ __launch_bounds__(256) void final_kernel(const unsigned short* __restrict__ y2,
                                                    const float* __restrict__ x,
                                                    const float* __restrict__ Wout,
                                                    const float* __restrict__ bout,
                                                    const float* __restrict__ Wskip,
                                                    float* __restrict__ out){
    int wave = threadIdx.x >> 6;
    int lane = threadIdx.x & 63;
    int t = blockIdx.x * 4 + wave;
    float s0 = 0.f, s1 = 0.f, s2 = 0.f, s3 = 0.f;
    const float4* W4 = (const float4*)Wout;
    #pragma unroll
    for (int k = lane; k < H; k += 64){
        float yv = bf2f(y2[(size_t)t * H + k]);
        float4 w = W4[k];
        s0 = fmaf(yv, w.x, s0); s1 = fmaf(yv, w.y, s1);
        s2 = fmaf(yv, w.z, s2); s3 = fmaf(yv, w.w, s3);
    }
    const float4* S4 = (const float4*)Wskip;
    #pragma unroll
    for (int k = lane; k < OBS; k += 64){
        float xv = x[(size_t)t * OBS + k];
        float4 w = S4[k];
        s0 = fmaf(xv, w.x, s0); s1 = fmaf(xv, w.y, s1);
        s2 = fmaf(xv, w.z, s2); s3 = fmaf(xv, w.w, s3);
    }
    #pragma unroll
    for (int off = 32; off > 0; off >>= 1){
        s0 += __shfl_down(s0, off);
        s1 += __shfl_down(s1, off);
        s2 += __shfl_down(s2, off);
        s3 += __shfl_down(s3, off);
    }
    if (lane == 0){
        out[(size_t)t * 4 + 0] = s0 + bout[0];
        out[(size_t)t * 4 + 1] = s1 + bout[1];
        out[(size_t)t * 4 + 2] = s2 + bout[2];
        out[(size_t)t * 4 + 3] = s3 + bout[3];
    }
}

extern "C" void kernel_launch(void* const* d_in, const int* in_sizes, int n_in,
                              void* d_out, int out_size, void* d_ws, size_t ws_size,
                              hipStream_t stream)
{
    const float* x     = (const float*)d_in[0];
    const float* W_in0 = (const float*)d_in[1];
    const float* W_B0  = (const float*)d_in[2];
    const float* W_C0  = (const float*)d_in[3];
    const float* W_d0  = (const float*)d_in[4];
    const float* A0    = (const float*)d_in[5];
    const float* W_in1 = (const float*)d_in[6];
    const float* W_B1  = (const float*)d_in[7];
    const float* W_C1  = (const float*)d_in[8];
    const float* W_d1  = (const float*)d_in[9];
    const float* A1    = (const float*)d_in[10];
    const float* Wout  = (const float*)d_in[11];
    const float* bout  = (const float*)d_in[12];
    const float* Wskip = (const float*)d_in[13];
    float* out = (float*)d_out;

    char* ws = (char*)d_ws;
    size_t off = 0;
    auto alloc = [&](size_t bytes) -> void* {
        void* p = ws + off;
        off += (bytes + 255) & ~(size_t)255;
        return p;
    };
    unsigned short* xb  = (unsigned short*)alloc((size_t)T_SIZE * OBS * 2);
    unsigned short* yb  = (unsigned short*)alloc((size_t)T_SIZE * H * 2);  // layer0 y; reused for layer1 y
    unsigned short* Wt0 = (unsigned short*)alloc((size_t)4 * H * OBS * 2);
    unsigned short* Wt1 = (unsigned short*)alloc((size_t)4 * H * H * 2);
    float*          aT  = (float*)alloc((size_t)T_SIZE * H * 4);
    unsigned short* bxT = (unsigned short*)alloc((size_t)T_SIZE * H * 2);
    unsigned short* CT  = (unsigned short*)alloc((size_t)T_SIZE * H * 2);
    float* Pbuf = (float*)alloc((size_t)NC * H * 4);
    float* Hbuf = (float*)alloc((size_t)NC * H * 4);
    float* Sloc = (float*)alloc((size_t)NC * H * 4);
    float* Pp   = (float*)alloc((size_t)NC * H * 4);
    float* Pg   = (float*)alloc((size_t)NGRP * H * 4);
    float* Hg   = (float*)alloc((size_t)NGRP * H * 4);
    float* Cg   = (float*)alloc((size_t)NGRP * H * 4);
    (void)ws_size; (void)in_sizes; (void)n_in; (void)out_size;

    // ---- precision casts / weight transposes (interleaved layout) ----
    cast_x_kernel<<<(T_SIZE * OBS / 4 + 255) / 256, 256, 0, stream>>>(x, xb, T_SIZE * OBS / 4);
    tcast4_kernel<<<(4 * OBS * H + 255) / 256, 256, 0, stream>>>(W_in0, W_B0, W_C0, W_d0, Wt0, OBS, OBS * H);
    tcast4_kernel<<<(4 * H   * H + 255) / 256, 256, 0, stream>>>(W_in1, W_B1, W_C1, W_d1, Wt1, H,   H * H);

    dim3 ggrid(16, 256);                 // flat-swizzled inside the kernel
    const int sgrid = NC * 128 / 256;    // 256 blocks

    // ---- layer 0 ----
    gemm_layer_kernel<<<ggrid, 256, 0, stream>>>(xb, Wt0, A0, aT, bxT, CT, Pbuf, Hbuf, OBS);
    scan2a_kernel<<<NGRP, 128, 0, stream>>>(Pbuf, Hbuf, Sloc, Pp, Pg, Hg);
    scan2b_kernel<<<1, H, 0, stream>>>(Pg, Hg, Cg);
    scan3_bf16_kernel<<<sgrid, 256, 0, stream>>>(aT, bxT, CT, Sloc, Pp, Cg, yb);

    // ---- layer 1 ----
    gemm_layer_kernel<<<ggrid, 256, 0, stream>>>(yb, Wt1, A1, aT, bxT, CT, Pbuf, Hbuf, H);
    scan2a_kernel<<<NGRP, 128, 0, stream>>>(Pbuf, Hbuf, Sloc, Pp, Pg, Hg);
    scan2b_kernel<<<1, H, 0, stream>>>(Pg, Hg, Cg);
    scan3_bf16_kernel<<<sgrid, 256, 0, stream>>>(aT, bxT, CT, Sloc, Pp, Cg, yb /*reuse: layer1 y*/);

    // ---- output head ----
    final_kernel<<<T_SIZE / 4, 256, 0, stream>>>(yb, x, Wout, bout, Wskip, out);
}

// Round 7
// 347.610 us; speedup vs baseline: 2.0358x; 1.0546x over previous
//
#include <hip/hip_runtime.h>

typedef __attribute__((ext_vector_type(8))) short short8;
typedef __attribute__((ext_vector_type(4))) float floatx4;

#define T_SIZE 32768
#define OBS    256
#define H      512
#define NC     512     // scan chunks
#define CHUNK  64      // T_SIZE / NC
#define NGRP   64      // scan2 groups
#define GCH    8       // chunks per group
#define SLAB   ((size_t)T_SIZE * 32)   // one h-block slab in tiled layout

__device__ __forceinline__ unsigned short f2bf(float f){
    union { float f; unsigned u; } v; v.f = f;
    unsigned u = v.u;
    u += 0x7FFFu + ((u >> 16) & 1u);   // round-to-nearest-even
    return (unsigned short)(u >> 16);
}
__device__ __forceinline__ float bf2f(unsigned short u){
    union { unsigned u; float f; } v; v.u = ((unsigned)u) << 16; return v.f;
}

// async global->LDS, 16B per lane; lds base must be wave-uniform (HW adds lane*16)
#define GLOAD_LDS16(g, l) \
    __builtin_amdgcn_global_load_lds((const __attribute__((address_space(1))) unsigned*)(g), \
                                     (__attribute__((address_space(3))) unsigned*)(l), 16, 0, 0)

// ---- cast x [T,OBS] fp32 -> bf16, vectorized ----
__global__ void cast_x_kernel(const float* __restrict__ x, unsigned short* __restrict__ xb, int n4){
    int i = blockIdx.x * 256 + threadIdx.x;
    if (i < n4){
        float4 v = ((const float4*)x)[i];
        ushort4 o;
        o.x = f2bf(v.x); o.y = f2bf(v.y); o.z = f2bf(v.z); o.w = f2bf(v.w);
        ((ushort4*)xb)[i] = o;
    }
}

// ---- transpose+cast 4 weights W[K][512] fp32 -> interleaved [h/16][slot][16h][K] bf16 ----
__global__ void tcast4_kernel(const float* __restrict__ W0, const float* __restrict__ W1,
                              const float* __restrict__ W2, const float* __restrict__ W3,
                              unsigned short* __restrict__ dst, int K, int KH){
    int idx = blockIdx.x * 256 + threadIdx.x;
    if (idx >= 4 * KH) return;
    int s   = idx / KH;
    int rem = idx - s * KH;
    int k = rem >> 9;            // H == 512
    int h = rem & 511;
    const float* W = (s == 0) ? W0 : (s == 1) ? W1 : (s == 2) ? W2 : W3;
    int b = h >> 4, hh = h & 15;
    dst[(size_t)((b * 4 + s) * 16 + hh) * K + k] = f2bf(W[(size_t)k * H + h]);
}

// ---- fused 4-matrix GEMM (dbuf LDS, 1 barrier/iter) + 1-round epilogue + scan1 fused ----
// xb: [T][K] bf16.  wt: [H/16][4 slots][16 h][K] bf16 (slot: 0=in,1=B,2=C,3=d).
// Outputs TILED bf16 [H/32][T][32]: gT (=delta*-exp(A_log)), bxT, CT.  Pbuf/Hbuf [NC][H] fp32.
// Scan aggregates are computed from the ROUNDED bf16 g/bx so they are consistent with scan3.
__global__ __launch_bounds__(256) void gemm_layer_kernel(
    const unsigned short* __restrict__ xb,
    const unsigned short* __restrict__ wt,
    const float* __restrict__ A_log,
    unsigned short* __restrict__ gT, unsigned short* __restrict__ bxT, unsigned short* __restrict__ CT,
    float* __restrict__ Pbuf, float* __restrict__ Hbuf,
    int K)
{
    // two 16 KB buffers: [buf][A(4096 shorts) | B(4096 shorts)]; epilogue reuses 24 KB
    __shared__ unsigned short SM[2][8192];

    const int tid  = threadIdx.x;
    const int wave = tid >> 6;
    const int lane = tid & 63;
    const int ml   = lane & 15;
    const int quad = lane >> 4;
    const int wm   = wave & 1;
    const int wn   = wave >> 1;

    // XCD-aware swizzle: all 16 nb-blocks of one mb land on one XCD (A-panel L2 reuse)
    const int flat = blockIdx.y * 16 + blockIdx.x;
    const int xcd  = flat & 7;
    const int j    = flat >> 3;
    const int nb   = j & 15;                 // 0..15 : h block of 32
    const int mb   = (j >> 4) * 8 + xcd;     // 0..255 : t tile of 128
    const int m0   = mb * 128;

    const int srow = tid >> 2;
    const int sel  = (((tid & 3) ^ ((tid >> 3) & 3))) * 8;   // staging XOR swizzle
    const int swz  = (ml >> 1) & 3;                          // read-side XOR swizzle

    const unsigned short* pa0 = xb + (size_t)(m0 + srow) * K + sel;
    const unsigned short* pa1 = pa0 + (size_t)64 * K;
    const unsigned short* pb0 = wt + (size_t)(nb * 128 + srow) * K + sel;
    const unsigned short* pb1 = pb0 + (size_t)64 * K;

    const int ldsA0 = (wave * 64 + 0  ) * 8;
    const int ldsA1 = (wave * 64 + 256) * 8;

    floatx4 acc[4][4];
    #pragma unroll
    for (int i = 0; i < 4; i++)
        #pragma unroll
        for (int jj = 0; jj < 4; jj++)
            acc[i][jj] = (floatx4)(0.0f);

    GLOAD_LDS16(pa0, &SM[0][ldsA0]);
    GLOAD_LDS16(pa1, &SM[0][ldsA1]);
    GLOAD_LDS16(pb0, &SM[0][4096 + ldsA0]);
    GLOAD_LDS16(pb1, &SM[0][4096 + ldsA1]);

    const int nk = K >> 5;
    for (int kk = 0; kk < nk; ++kk){
        __syncthreads();
        const int cur = kk & 1;
        if (kk + 1 < nk){
            const int nxt = cur ^ 1;
            const int ko  = (kk + 1) * 32;
            GLOAD_LDS16(pa0 + ko, &SM[nxt][ldsA0]);
            GLOAD_LDS16(pa1 + ko, &SM[nxt][ldsA1]);
            GLOAD_LDS16(pb0 + ko, &SM[nxt][4096 + ldsA0]);
            GLOAD_LDS16(pb1 + ko, &SM[nxt][4096 + ldsA1]);
        }

        const unsigned short* As = &SM[cur][0];
        const unsigned short* Bs = &SM[cur][4096];
        short8 av[4], bv[4];
        #pragma unroll
        for (int i = 0; i < 4; i++)
            av[i] = *(const short8*)(As + (size_t)(wm * 64 + i * 16 + ml) * 32 + (quad ^ swz) * 8);
        #pragma unroll
        for (int jj = 0; jj < 4; jj++)
            bv[jj] = *(const short8*)(Bs + (size_t)(wn * 64 + jj * 16 + ml) * 32 + (quad ^ swz) * 8);

        #pragma unroll
        for (int i = 0; i < 4; i++)
            #pragma unroll
            for (int jj = 0; jj < 4; jj++)
                acc[i][jj] = __builtin_amdgcn_mfma_f32_16x16x32_bf16(av[i], bv[jj], acc[i][jj], 0, 0, 0);
    }
    __syncthreads();   // all LDS reads done before epilogue reuses SM

    // ---- epilogue: slots 0=x_state, 1=B, 2=C, 3=d.  One 24 KB LDS round. ----
    unsigned short* SMe = &SM[0][0];        // 16384 shorts available; use 12288
    const int col = wn * 16 + ml;           // 0..31 h within block
    const int h   = nb * 32 + col;
    const float Aneg = -expf(A_log[h]);

    float segp[4], segh[4];                 // per-i 4-step scan segment aggregates (chunk = wm)
    #pragma unroll
    for (int i = 0; i < 4; i++){
        float p = 1.0f, hh = 0.0f;
        #pragma unroll
        for (int r = 0; r < 4; r++){
            int trow = wm * 64 + i * 16 + quad * 4 + r;   // C/D: row = quad*4 + reg
            float dv = acc[i][3][r];
            float delta = 1.0f / (1.0f + expf(-dv));
            unsigned short gb = f2bf(delta * Aneg);
            float a = expf(bf2f(gb));                     // rounded -> consistent with scan3
            unsigned short bb = f2bf(acc[i][1][r] * acc[i][0][r]);
            SMe[        trow * 32 + col] = gb;
            SMe[4096 +  trow * 32 + col] = bb;
            SMe[8192 +  trow * 32 + col] = f2bf(acc[i][2][r]);
            hh = fmaf(a, hh, bf2f(bb));
            p *= a;
        }
        segp[i] = p; segh[i] = hh;
    }
    __syncthreads();
    {
        const short8* s8 = (const short8*)SMe;
        short8* dg = (short8*)(gT  + (size_t)nb * SLAB + (size_t)m0 * 32);
        short8* db = (short8*)(bxT + (size_t)nb * SLAB + (size_t)m0 * 32);
        short8* dc = (short8*)(CT  + (size_t)nb * SLAB + (size_t)m0 * 32);
        dg[tid] = s8[tid];        dg[tid + 256] = s8[tid + 256];
        db[tid] = s8[512 + tid];  db[tid + 256] = s8[768 + tid];
        dc[tid] = s8[1024 + tid]; dc[tid + 256] = s8[1280 + tid];
    }
    __syncthreads();

    // compose the 16 ordered segments per (chunk, col) -> chunk aggregates (scan1)
    float2* segbuf = (float2*)SMe;          // [seg 16][col 32][chunk 2] = 8 KB
    #pragma unroll
    for (int i = 0; i < 4; i++)
        segbuf[(i * 4 + quad) * 64 + col * 2 + wm] = make_float2(segp[i], segh[i]);
    __syncthreads();
    if (tid < 64){
        int ccol = tid >> 1, ch = tid & 1;
        float P = 1.0f, Hc = 0.0f;
        #pragma unroll
        for (int s = 0; s < 16; s++){
            float2 ph = segbuf[s * 64 + ccol * 2 + ch];
            Hc = fmaf(ph.x, Hc, ph.y);
            P *= ph.x;
        }
        int c = mb * 2 + ch;
        Pbuf[(size_t)c * H + nb * 32 + ccol] = P;
        Hbuf[(size_t)c * H + nb * 32 + ccol] = Hc;
    }
}

// ---- scan pass 2a: 64 groups x 8 chunks -> group aggregates only ----
__global__ void scan2a_kernel(const float* __restrict__ P, const float* __restrict__ Hc,
                              float* __restrict__ Pg, float* __restrict__ Hg){
    const int g  = blockIdx.x;          // 0..63
    const int j4 = threadIdx.x * 4;     // 128 threads
    float4 pc = {1.f,1.f,1.f,1.f}, hc = {0.f,0.f,0.f,0.f};
    #pragma unroll
    for (int i = 0; i < GCH; i++){
        size_t o = (size_t)(g * GCH + i) * H + j4;
        float4 P4 = *(const float4*)(P + o);
        float4 H4 = *(const float4*)(Hc + o);
        hc.x = fmaf(P4.x, hc.x, H4.x); pc.x *= P4.x;
        hc.y = fmaf(P4.y, hc.y, H4.y); pc.y *= P4.y;
        hc.z = fmaf(P4.z, hc.z, H4.z); pc.z *= P4.z;
        hc.w = fmaf(P4.w, hc.w, H4.w); pc.w *= P4.w;
    }
    *(float4*)(Pg + (size_t)g * H + j4) = pc;
    *(float4*)(Hg + (size_t)g * H + j4) = hc;
}

// ---- scan pass 2b: sequential exclusive combine over 64 groups (1 block, 512 threads) ----
__global__ void scan2b_kernel(const float* __restrict__ Pg, const float* __restrict__ Hg,
                              float* __restrict__ Cg){
    const int j = threadIdx.x;
    float carry = 0.0f;
    for (int g0 = 0; g0 < NGRP; g0 += 8){
        float p[8], h[8];
        #pragma unroll
        for (int i = 0; i < 8; i++){
            p[i] = Pg[(size_t)(g0 + i) * H + j];
            h[i] = Hg[(size_t)(g0 + i) * H + j];
        }
        #pragma unroll
        for (int i = 0; i < 8; i++){
            Cg[(size_t)(g0 + i) * H + j] = carry;
            carry = fmaf(p[i], carry, h[i]);
        }
    }
}

// ---- scan pass 3: h0 = fold(group prefix) from Pbuf/Hbuf + Cg; apply; y=C*h bf16 [T][H] ----
__global__ void scan3_kernel(const unsigned short* __restrict__ gT, const unsigned short* __restrict__ bxT,
                             const unsigned short* __restrict__ CT,
                             const float* __restrict__ P, const float* __restrict__ Hc,
                             const float* __restrict__ Cg,
                             unsigned short* __restrict__ yb){
    int idx = blockIdx.x * 256 + threadIdx.x;
    int j4 = (idx & 127) * 4;
    int c  = idx >> 7;                  // wave-uniform
    int nb = j4 >> 5, jj = j4 & 31;
    int grp = c >> 3;                   // NC/GCH = 64 groups
    float4 h = *(const float4*)(Cg + (size_t)grp * H + j4);
    for (int cc = grp << 3; cc < c; ++cc){          // <=7 L2-hot folds, wave-uniform count
        float4 P4 = *(const float4*)(P + (size_t)cc * H + j4);
        float4 H4 = *(const float4*)(Hc + (size_t)cc * H + j4);
        h.x = fmaf(P4.x, h.x, H4.x);
        h.y = fmaf(P4.y, h.y, H4.y);
        h.z = fmaf(P4.z, h.z, H4.z);
        h.w = fmaf(P4.w, h.w, H4.w);
    }
    size_t off = (size_t)nb * SLAB + (size_t)c * CHUNK * 32 + jj;
    size_t yo  = (size_t)c * CHUNK * H + j4;
    #pragma unroll 8
    for (int i = 0; i < CHUNK; i++){
        ushort4 gv = *(const ushort4*)(gT + off);
        ushort4 bv = *(const ushort4*)(bxT + off);
        ushort4 cv = *(const ushort4*)(CT + off);
        h.x = fmaf(expf(bf2f(gv.x)), h.x, bf2f(bv.x));
        h.y = fmaf(expf(bf2f(gv.y)), h.y, bf2f(bv.y));
        h.z = fmaf(expf(bf2f(gv.z)), h.z, bf2f(bv.z));
        h.w = fmaf(expf(bf2f(gv.w)), h.w, bf2f(bv.w));
        ushort4 o;
        o.x = f2bf(bf2f(cv.x) * h.x);
        o.y = f2bf(bf2f(cv.y) * h.y);
        o.z = f2bf(bf2f(cv.z) * h.z);
        o.w = f2bf(bf2f(cv.w) * h.w);
        *(ushort4*)(yb + yo) = o;
        off += 32; yo += H;
    }
}

// ---- final: out[t][0:4] = y[t]@W_out + b_out + xb[t]@W_skip  (y,xb bf16; wave per row) ----
__global__ __launch_bounds__(256) void final_kernel(const unsigned short* __restrict__ y2,
                                                    const unsigned short* __restrict__ xb,
                                                    const float* __restrict__ Wout,
                                                    const float* __restrict__ bout,
                                                    const float* __restrict__ Wskip,
                                                    float* __restrict__ out){
    int wave = threadIdx.x >> 6;
    int lane = threadIdx.x & 63;
    int t = blockIdx.x * 4 + wave;
    float s0 = 0.f, s1 = 0.f, s2 = 0.f, s3 = 0.f;
    const float4* W4 = (const float4*)Wout;
    #pragma unroll
    for (int k = lane; k < H; k += 64){
        float yv = bf2f(y2[(size_t)t * H + k]);
        float4 w = W4[k];
        s0 = fmaf(yv, w.x, s0); s1 = fmaf(yv, w.y, s1);
        s2 = fmaf(yv, w.z, s2); s3 = fmaf(yv, w.w, s3);
    }
    const float4* S4 = (const float4*)Wskip;
    #pragma unroll
    for (int k = lane; k < OBS; k += 64){
        float xv = bf2f(xb[(size_t)t * OBS + k]);
        float4 w = S4[k];
        s0 = fmaf(xv, w.x, s0); s1 = fmaf(xv, w.y, s1);
        s2 = fmaf(xv, w.z, s2); s3 = fmaf(xv, w.w, s3);
    }
    #pragma unroll
    for (int off = 32; off > 0; off >>= 1){
        s0 += __shfl_down(s0, off);
        s1 += __shfl_down(s1, off);
        s2 += __shfl_down(s2, off);
        s3 += __shfl_down(s3, off);
    }
    if (lane == 0){
        out[(size_t)t * 4 + 0] = s0 + bout[0];
        out[(size_t)t * 4 + 1] = s1 + bout[1];
        out[(size_t)t * 4 + 2] = s2 + bout[2];
        out[(size_t)t * 4 + 3] = s3 + bout[3];
    }
}

extern "C" void kernel_launch(void* const* d_in, const int* in_sizes, int n_in,
                              void* d_out, int out_size, void* d_ws, size_t ws_size,
                              hipStream_t stream)
{
    const float* x     = (const float*)d_in[0];
    const float* W_in0 = (const float*)d_in[1];
    const float* W_B0  = (const float*)d_in[2];
    const float* W_C0  = (const float*)d_in[3];
    const float* W_d0  = (const float*)d_in[4];
    const float* A0    = (const float*)d_in[5];
    const float* W_in1 = (const float*)d_in[6];
    const float* W_B1  = (const float*)d_in[7];
    const float* W_C1  = (const float*)d_in[8];
    const float* W_d1  = (const float*)d_in[9];
    const float* A1    = (const float*)d_in[10];
    const float* Wout  = (const float*)d_in[11];
    const float* bout  = (const float*)d_in[12];
    const float* Wskip = (const float*)d_in[13];
    float* out = (float*)d_out;

    char* ws = (char*)d_ws;
    size_t off = 0;
    auto alloc = [&](size_t bytes) -> void* {
        void* p = ws + off;
        off += (bytes + 255) & ~(size_t)255;
        return p;
    };
    unsigned short* xb  = (unsigned short*)alloc((size_t)T_SIZE * OBS * 2);
    unsigned short* yb  = (unsigned short*)alloc((size_t)T_SIZE * H * 2);  // layer0 y; reused for layer1 y
    unsigned short* Wt0 = (unsigned short*)alloc((size_t)4 * H * OBS * 2);
    unsigned short* Wt1 = (unsigned short*)alloc((size_t)4 * H * H * 2);
    unsigned short* gT  = (unsigned short*)alloc((size_t)T_SIZE * H * 2);
    unsigned short* bxT = (unsigned short*)alloc((size_t)T_SIZE * H * 2);
    unsigned short* CT  = (unsigned short*)alloc((size_t)T_SIZE * H * 2);
    float* Pbuf = (float*)alloc((size_t)NC * H * 4);
    float* Hbuf = (float*)alloc((size_t)NC * H * 4);
    float* Pg   = (float*)alloc((size_t)NGRP * H * 4);
    float* Hg   = (float*)alloc((size_t)NGRP * H * 4);
    float* Cg   = (float*)alloc((size_t)NGRP * H * 4);
    (void)ws_size; (void)in_sizes; (void)n_in; (void)out_size;

    // ---- precision casts / weight transposes (interleaved layout) ----
    cast_x_kernel<<<(T_SIZE * OBS / 4 + 255) / 256, 256, 0, stream>>>(x, xb, T_SIZE * OBS / 4);
    tcast4_kernel<<<(4 * OBS * H + 255) / 256, 256, 0, stream>>>(W_in0, W_B0, W_C0, W_d0, Wt0, OBS, OBS * H);
    tcast4_kernel<<<(4 * H   * H + 255) / 256, 256, 0, stream>>>(W_in1, W_B1, W_C1, W_d1, Wt1, H,   H * H);

    dim3 ggrid(16, 256);                 // flat-swizzled inside the kernel
    const int sgrid = NC * 128 / 256;    // 256 blocks

    // ---- layer 0 ----
    gemm_layer_kernel<<<ggrid, 256, 0, stream>>>(xb, Wt0, A0, gT, bxT, CT, Pbuf, Hbuf, OBS);
    scan2a_kernel<<<NGRP, 128, 0, stream>>>(Pbuf, Hbuf, Pg, Hg);
    scan2b_kernel<<<1, H, 0, stream>>>(Pg, Hg, Cg);
    scan3_kernel<<<sgrid, 256, 0, stream>>>(gT, bxT, CT, Pbuf, Hbuf, Cg, yb);

    // ---- layer 1 ----
    gemm_layer_kernel<<<ggrid, 256, 0, stream>>>(yb, Wt1, A1, gT, bxT, CT, Pbuf, Hbuf, H);
    scan2a_kernel<<<NGRP, 128, 0, stream>>>(Pbuf, Hbuf, Pg, Hg);
    scan2b_kernel<<<1, H, 0, stream>>>(Pg, Hg, Cg);
    scan3_kernel<<<sgrid, 256, 0, stream>>>(gT, bxT, CT, Pbuf, Hbuf, Cg, yb /*reuse: layer1 y*/);

    // ---- output head ----
    final_kernel<<<T_SIZE / 4, 256, 0, stream>>>(yb, xb, Wout, bout, Wskip, out);
}